// Round 1
// baseline (564.616 us; speedup 1.0000x reference)
//
#include <hip/hip_runtime.h>
#include <cstdint>
#include <cstddef>

typedef unsigned short ushort_t;
typedef __attribute__((ext_vector_type(8))) short s8v;
typedef __attribute__((ext_vector_type(4))) short s4v;
typedef __attribute__((ext_vector_type(4))) float f4v;

#define MFMA16(a, b, c) __builtin_amdgcn_mfma_f32_16x16x32_bf16(a, b, c, 0, 0, 0)

__device__ __forceinline__ ushort_t f2bf(float f) {
  union { float f; unsigned u; } a; a.f = f;
  return (ushort_t)((a.u + 0x7fffu + ((a.u >> 16) & 1u)) >> 16);
}
__device__ __forceinline__ float bf2f(ushort_t h) {
  union { unsigned u; float f; } a; a.u = ((unsigned)h) << 16; return a.f;
}

// async global->LDS, 16B per lane; LDS dest is wave-uniform base + lane*16
__device__ __forceinline__ void gload16(const void* g, void* l) {
  __builtin_amdgcn_global_load_lds(
      (__attribute__((address_space(1))) void*)(uintptr_t)g,
      (__attribute__((address_space(3))) void*)(unsigned)(uintptr_t)l,
      16, 0, 0);
}

// ---------------------------------------------------------------------------
// 1) fp32 -> bf16 weight conversion. grid = 12288 blocks x 256 (1024 elem/blk)
// ---------------------------------------------------------------------------
__launch_bounds__(256)
__global__ void convert_w(const float* __restrict__ wq, const float* __restrict__ wk,
                          const float* __restrict__ wv, const float* __restrict__ wo,
                          const float* __restrict__ f1, const float* __restrict__ f2,
                          ushort_t* __restrict__ dqkv, ushort_t* __restrict__ dwo,
                          ushort_t* __restrict__ df1, ushort_t* __restrict__ df2)
{
  const int blk = blockIdx.x;
  const float* src; ushort_t* dst; int off;
  if      (blk < 1024) { src = wq; dst = dqkv;            off = blk; }
  else if (blk < 2048) { src = wk; dst = dqkv + 1048576;  off = blk - 1024; }
  else if (blk < 3072) { src = wv; dst = dqkv + 2097152;  off = blk - 2048; }
  else if (blk < 4096) { src = wo; dst = dwo;             off = blk - 3072; }
  else if (blk < 8192) { src = f1; dst = df1;             off = blk - 4096; }
  else                 { src = f2; dst = df2;             off = blk - 8192; }
  const int idx = off * 1024 + threadIdx.x * 4;
  float4 v = *(const float4*)(src + idx);
  s4v o;
  o[0] = (short)f2bf(v.x); o[1] = (short)f2bf(v.y);
  o[2] = (short)f2bf(v.z); o[3] = (short)f2bf(v.w);
  *(s4v*)(dst + idx) = o;
}

// ---------------------------------------------------------------------------
// 2) adaln: emb[b][j] = sum_d silu(ts[b][d]) * w[j][d] + bias[j]
//    one wave per j, both batches. grid = 1536 x 256
// ---------------------------------------------------------------------------
__launch_bounds__(256)
__global__ void adaln(const float* __restrict__ ts, const float* __restrict__ w,
                      const float* __restrict__ bias, float* __restrict__ emb)
{
  const int j = blockIdx.x * 4 + (threadIdx.x >> 6);
  const int lane = threadIdx.x & 63;
  const float* wr = w + (size_t)j * 1024;
  float s0 = 0.f, s1 = 0.f;
  for (int i = lane; i < 1024; i += 64) {
    const float wv = wr[i];
    const float t0 = ts[i], t1 = ts[1024 + i];
    s0 += wv * (t0 / (1.f + __expf(-t0)));
    s1 += wv * (t1 / (1.f + __expf(-t1)));
  }
  #pragma unroll
  for (int m = 32; m; m >>= 1) { s0 += __shfl_down(s0, m); s1 += __shfl_down(s1, m); }
  if (!lane) { emb[j] = s0 + bias[j]; emb[6144 + j] = s1 + bias[j]; }
}

// ---------------------------------------------------------------------------
// 3) LayerNorm + msa modulation -> xm bf16. one block per row.
// ---------------------------------------------------------------------------
__launch_bounds__(256)
__global__ void ln_mod(const float* __restrict__ x, const float* __restrict__ emb,
                       ushort_t* __restrict__ xm)
{
  const int row = blockIdx.x, b = row >> 11, tid = threadIdx.x;
  const float* xr = x + (size_t)row * 1024;
  const int c = tid * 4;
  float4 v = *(const float4*)(xr + c);
  float s  = v.x + v.y + v.z + v.w;
  float s2 = v.x*v.x + v.y*v.y + v.z*v.z + v.w*v.w;
  #pragma unroll
  for (int m = 32; m; m >>= 1) { s += __shfl_down(s, m); s2 += __shfl_down(s2, m); }
  __shared__ float red[8];
  const int wave = tid >> 6, lane = tid & 63;
  if (!lane) { red[wave] = s; red[4 + wave] = s2; }
  __syncthreads();
  const float mu = (red[0] + red[1] + red[2] + red[3]) * (1.f / 1024.f);
  const float ms = (red[4] + red[5] + red[6] + red[7]) * (1.f / 1024.f);
  const float rstd = rsqrtf(ms - mu * mu + 1e-6f);
  const float* sh = emb + b * 6144;
  const float* sc = emb + b * 6144 + 1024;
  float4 shv = *(const float4*)(sh + c);
  float4 scv = *(const float4*)(sc + c);
  s4v ov;
  ov[0] = (short)f2bf((v.x - mu) * rstd * (1.f + scv.x) + shv.x);
  ov[1] = (short)f2bf((v.y - mu) * rstd * (1.f + scv.y) + shv.y);
  ov[2] = (short)f2bf((v.z - mu) * rstd * (1.f + scv.z) + shv.z);
  ov[3] = (short)f2bf((v.w - mu) * rstd * (1.f + scv.w) + shv.w);
  *(s4v*)(xm + (size_t)row * 1024 + c) = ov;
}

// ---------------------------------------------------------------------------
// 4) bf16 B^T GEMM, m97 structure: 128x128 tile, BK=32, global_load_lds(16B),
//    16x16x32 MFMA, 4x4 acc per wave. out[i,j] = sum_k A[i,k]*Bw[j,k] (+epi)
//    EPI: 0 = bf16 store, 1 = h = x + g_msa*o (fp32), 2 = bias+gelu (bf16),
//         3 = out = h + g_mlp*(v+bias) (fp32)
// ---------------------------------------------------------------------------
template<int EPI>
__launch_bounds__(256)
__global__ void gemm_bt(const ushort_t* __restrict__ A, const ushort_t* __restrict__ Bw,
                        int K, int N,
                        ushort_t* __restrict__ outb, float* __restrict__ outf,
                        const float* __restrict__ bias, const float* __restrict__ resid,
                        const float* __restrict__ emb, int gate_off)
{
  __shared__ ushort_t As[128 * 32];
  __shared__ ushort_t Bs[128 * 32];
  const int tid = threadIdx.x;
  const int wave = tid >> 6, lane = tid & 63;
  const int quad = lane >> 4, r = lane & 15;
  const int m0 = blockIdx.y * 128, n0 = blockIdx.x * 128;
  const int wm = (wave >> 1) * 64, wn = (wave & 1) * 64;

  // staging: thread covers row (wave*16 + lane/4) [+64], k-bytes (lane&3)*16
  const int srow = wave * 16 + (lane >> 2);
  const int scol = (lane & 3) * 8;
  const ushort_t* ag = A  + (size_t)(m0 + srow) * K + scol;
  const ushort_t* bg = Bw + (size_t)(n0 + srow) * K + scol;
  const size_t rowK64 = (size_t)64 * K;
  ushort_t* as0 = As + wave * 512;
  ushort_t* as1 = As + 2048 + wave * 512;
  ushort_t* bs0 = Bs + wave * 512;
  ushort_t* bs1 = Bs + 2048 + wave * 512;

  f4v acc[4][4] = {};

  for (int k0 = 0; k0 < K; k0 += 32) {
    __syncthreads();                      // all waves done reading previous tile
    gload16(ag,          as0);
    gload16(ag + rowK64, as1);
    gload16(bg,          bs0);
    gload16(bg + rowK64, bs1);
    ag += 32; bg += 32;
    __syncthreads();                      // drains vmcnt -> LDS tile visible
    s8v af[4], bf[4];
    #pragma unroll
    for (int i = 0; i < 4; i++)
      af[i] = *(const s8v*)(As + (wm + i * 16 + r) * 32 + quad * 8);
    #pragma unroll
    for (int i = 0; i < 4; i++)
      bf[i] = *(const s8v*)(Bs + (wn + i * 16 + r) * 32 + quad * 8);
    #pragma unroll
    for (int i = 0; i < 4; i++)
      #pragma unroll
      for (int j = 0; j < 4; j++)
        acc[i][j] = MFMA16(af[i], bf[j], acc[i][j]);
  }

  #pragma unroll
  for (int i = 0; i < 4; i++) {
    const int row = m0 + wm + i * 16 + quad * 4;
    #pragma unroll
    for (int j = 0; j < 4; j++) {
      const int col = n0 + wn + j * 16 + r;
      #pragma unroll
      for (int rr = 0; rr < 4; rr++) {
        float v = acc[i][j][rr];
        const int rw = row + rr;
        const size_t idx = (size_t)rw * N + col;
        if (EPI == 0) {
          outb[idx] = f2bf(v);
        } else if (EPI == 1) {
          const int b = rw >> 11;
          outf[idx] = resid[idx] + emb[b * 6144 + gate_off + col] * v;
        } else if (EPI == 2) {
          v += bias[col];
          const float u = 0.7978845608028654f * (v + 0.044715f * v * v * v);
          const float e = __expf(2.f * u);
          const float th = 1.f - 2.f / (e + 1.f);     // tanh(u), inf-safe
          outb[idx] = f2bf(0.5f * v * (1.f + th));
        } else {
          const int b = rw >> 11;
          outf[idx] = resid[idx] + emb[b * 6144 + gate_off + col] * (v + bias[col]);
        }
      }
    }
  }
}

// ---------------------------------------------------------------------------
// 5) QKV post: RMSNorm(q,k over 1024) + RoPE + [B,H,S,HD] bf16 layout.
// ---------------------------------------------------------------------------
__launch_bounds__(256)
__global__ void qkv_post(const ushort_t* __restrict__ qkv, const float* __restrict__ rope,
                         const float* __restrict__ qw, const float* __restrict__ kw,
                         ushort_t* __restrict__ q_r, ushort_t* __restrict__ k_r,
                         ushort_t* __restrict__ v_r)
{
  const int row = blockIdx.x, b = row >> 11, s = row & 2047, tid = threadIdx.x;
  const ushort_t* base = qkv + (size_t)row * 3072;
  const int c = tid * 4;
  s4v qv = *(const s4v*)(base + c);
  s4v kv = *(const s4v*)(base + 1024 + c);
  s4v vv = *(const s4v*)(base + 2048 + c);
  float qf[4], kf[4]; float sq = 0.f, sk = 0.f;
  #pragma unroll
  for (int i = 0; i < 4; i++) {
    qf[i] = bf2f((ushort_t)qv[i]); kf[i] = bf2f((ushort_t)kv[i]);
    sq += qf[i] * qf[i]; sk += kf[i] * kf[i];
  }
  #pragma unroll
  for (int m = 32; m; m >>= 1) { sq += __shfl_down(sq, m); sk += __shfl_down(sk, m); }
  __shared__ float red[8];
  const int wave = tid >> 6, lane = tid & 63;
  if (!lane) { red[wave] = sq; red[4 + wave] = sk; }
  __syncthreads();
  const float rq = rsqrtf((red[0]+red[1]+red[2]+red[3]) * (1.f/1024.f) + 1e-6f);
  const float rk = rsqrtf((red[4]+red[5]+red[6]+red[7]) * (1.f/1024.f) + 1e-6f);

  const int h = c >> 6, d = c & 63;
  const float* rp = rope + ((size_t)s * 64 + d) * 2;   // [s][hd][{cos,sin}]
  float4 r01 = *(const float4*)(rp);
  float4 r23 = *(const float4*)(rp + 4);
  const float q0 = qf[0]*rq*qw[c], q1 = qf[1]*rq*qw[c+1];
  const float q2 = qf[2]*rq*qw[c+2], q3 = qf[3]*rq*qw[c+3];
  const float k0 = kf[0]*rk*kw[c], k1 = kf[1]*rk*kw[c+1];
  const float k2 = kf[2]*rk*kw[c+2], k3 = kf[3]*rk*kw[c+3];
  s4v qo, ko;
  qo[0] = (short)f2bf(q0 * r01.x - q1 * r01.y);
  qo[1] = (short)f2bf(q1 * r01.z + q0 * r01.w);
  qo[2] = (short)f2bf(q2 * r23.x - q3 * r23.y);
  qo[3] = (short)f2bf(q3 * r23.z + q2 * r23.w);
  ko[0] = (short)f2bf(k0 * r01.x - k1 * r01.y);
  ko[1] = (short)f2bf(k1 * r01.z + k0 * r01.w);
  ko[2] = (short)f2bf(k2 * r23.x - k3 * r23.y);
  ko[3] = (short)f2bf(k3 * r23.z + k2 * r23.w);
  const size_t out = ((size_t)(b * 16 + h) * 2048 + s) * 64 + d;
  *(s4v*)(q_r + out) = qo;
  *(s4v*)(k_r + out) = ko;
  *(s4v*)(v_r + out) = vv;
}

// ---------------------------------------------------------------------------
// 6) V transpose: [B,H,S,HD] -> [B,H,HD,S]. 64x64 tiles.
// ---------------------------------------------------------------------------
__launch_bounds__(256)
__global__ void vtrans(const ushort_t* __restrict__ v_r, ushort_t* __restrict__ v_t)
{
  const int bh = blockIdx.x >> 5, st = blockIdx.x & 31;
  const int s0 = st * 64;
  __shared__ ushort_t tile[64 * 72];    // 144B rows (16B aligned, bank-spread)
  const int tid = threadIdx.x;
  #pragma unroll
  for (int rep = 0; rep < 2; rep++) {
    const int idx = rep * 256 + tid;
    const int sr = idx >> 3, dc = (idx & 7) << 3;
    s8v val = *(const s8v*)(v_r + ((size_t)bh * 2048 + s0 + sr) * 64 + dc);
    *(s8v*)(tile + sr * 72 + dc) = val;
  }
  __syncthreads();
  #pragma unroll
  for (int rep = 0; rep < 2; rep++) {
    const int idx = rep * 256 + tid;
    const int d = idx >> 3, sc = (idx & 7) << 3;
    s8v val;
    #pragma unroll
    for (int j = 0; j < 8; j++) val[j] = (short)tile[(sc + j) * 72 + d];
    *(s8v*)(v_t + ((size_t)bh * 64 + d) * 2048 + s0 + sc) = val;
  }
}

// ---------------------------------------------------------------------------
// 7) Flash attention. block = (b,h, 64 q-rows); wave = 16 q-rows; 32-key tiles.
//    QK^T MFMA -> online softmax (quad-local shfl) -> P via LDS -> PV MFMA.
//    Writes attn in [B,S,H*HD] bf16 directly.
// ---------------------------------------------------------------------------
__launch_bounds__(256)
__global__ void flash(const ushort_t* __restrict__ q_r, const ushort_t* __restrict__ k_r,
                      const ushort_t* __restrict__ v_t, ushort_t* __restrict__ attn)
{
  __shared__ ushort_t Ksh[32 * 64];     // XOR-swizzled 16B chunks
  __shared__ ushort_t VT[64 * 32];      // [dim][key]
  __shared__ ushort_t Psh[4][16 * 32];  // per-wave P roundtrip
  const int bh = blockIdx.x >> 5, qb = blockIdx.x & 31;
  const int tid = threadIdx.x, wave = tid >> 6, lane = tid & 63;
  const int quad = lane >> 4, r = lane & 15;
  const int q0 = qb * 64 + wave * 16;
  const size_t bhS = (size_t)bh * 2048;

  s8v aq0 = *(const s8v*)(q_r + (bhS + q0 + r) * 64 + quad * 8);
  s8v aq1 = *(const s8v*)(q_r + (bhS + q0 + r) * 64 + 32 + quad * 8);

  f4v o[4] = {};
  float mi[4], li[4];
  #pragma unroll
  for (int rr = 0; rr < 4; rr++) { mi[rr] = -1e30f; li[rr] = 0.f; }

  const int skey = tid >> 3, sch = tid & 7;
  const ushort_t* kg = k_r + (bhS + skey) * 64 + sch * 8;
  ushort_t* kl = Ksh + skey * 64 + (((sch ^ (skey & 7))) << 3);
  const int vd = tid >> 2, vsc = tid & 3;
  const ushort_t* vg = v_t + ((size_t)bh * 64 + vd) * 2048 + vsc * 8;
  ushort_t* vl = VT + vd * 32 + vsc * 8;

  const int swz0 = ((0 + quad) ^ (r & 7)) << 3;
  const int swz1 = ((4 + quad) ^ (r & 7)) << 3;

  for (int kb = 0; kb < 2048; kb += 32) {
    __syncthreads();
    *(s8v*)kl = *(const s8v*)kg; kg += 32 * 64;
    *(s8v*)vl = *(const s8v*)vg; vg += 32;
    __syncthreads();

    f4v s0 = {}, s1 = {};
    s0 = MFMA16(aq0, *(const s8v*)(Ksh + r * 64 + swz0), s0);
    s0 = MFMA16(aq1, *(const s8v*)(Ksh + r * 64 + swz1), s0);
    s1 = MFMA16(aq0, *(const s8v*)(Ksh + (16 + r) * 64 + swz0), s1);
    s1 = MFMA16(aq1, *(const s8v*)(Ksh + (16 + r) * 64 + swz1), s1);

    float alpha[4];
    #pragma unroll
    for (int rr = 0; rr < 4; rr++) {
      const float sa = s0[rr] * 0.125f, sb = s1[rr] * 0.125f;
      float mx = fmaxf(sa, sb);
      #pragma unroll
      for (int msk = 1; msk < 16; msk <<= 1) mx = fmaxf(mx, __shfl_xor(mx, msk));
      const float mn = fmaxf(mi[rr], mx);
      const float al = __expf(mi[rr] - mn);
      const float p0 = __expf(sa - mn), p1 = __expf(sb - mn);
      float rs = p0 + p1;
      #pragma unroll
      for (int msk = 1; msk < 16; msk <<= 1) rs += __shfl_xor(rs, msk);
      li[rr] = al * li[rr] + rs;
      mi[rr] = mn;
      alpha[rr] = al;
      Psh[wave][(quad * 4 + rr) * 32 + r]      = f2bf(p0);
      Psh[wave][(quad * 4 + rr) * 32 + 16 + r] = f2bf(p1);
    }
    #pragma unroll
    for (int nt = 0; nt < 4; nt++) {
      #pragma unroll
      for (int rr = 0; rr < 4; rr++) o[nt][rr] *= alpha[rr];
    }
    asm volatile("s_waitcnt lgkmcnt(0)" ::: "memory");  // P writes -> reads (same wave)
    s8v ap = *(const s8v*)(&Psh[wave][0] + r * 32 + quad * 8);
    #pragma unroll
    for (int nt = 0; nt < 4; nt++) {
      s8v bv = *(const s8v*)(VT + (nt * 16 + r) * 32 + quad * 8);
      o[nt] = MFMA16(ap, bv, o[nt]);
    }
  }

  const int h = bh & 15, b = bh >> 4;
  #pragma unroll
  for (int rr = 0; rr < 4; rr++) {
    const float inv = 1.f / li[rr];
    const size_t orow = ((size_t)(b * 2048 + q0 + quad * 4 + rr)) * 1024 + h * 64;
    #pragma unroll
    for (int nt = 0; nt < 4; nt++)
      attn[orow + nt * 16 + r] = f2bf(o[nt][rr] * inv);
  }
}

// ---------------------------------------------------------------------------
// 8) RMSNorm3 + mlp modulation -> nm bf16
// ---------------------------------------------------------------------------
__launch_bounds__(256)
__global__ void rms3_mod(const float* __restrict__ h, const float* __restrict__ emb,
                         const float* __restrict__ w3, ushort_t* __restrict__ nm)
{
  const int row = blockIdx.x, b = row >> 11, tid = threadIdx.x;
  const float* hr = h + (size_t)row * 1024;
  const int c = tid * 4;
  float4 v = *(const float4*)(hr + c);
  float s2 = v.x*v.x + v.y*v.y + v.z*v.z + v.w*v.w;
  #pragma unroll
  for (int m = 32; m; m >>= 1) s2 += __shfl_down(s2, m);
  __shared__ float red[4];
  const int wave = tid >> 6, lane = tid & 63;
  if (!lane) red[wave] = s2;
  __syncthreads();
  const float rms = rsqrtf((red[0] + red[1] + red[2] + red[3]) * (1.f / 1024.f) + 1e-6f);
  const float* sh = emb + b * 6144 + 3072;
  const float* sc = emb + b * 6144 + 4096;
  float4 shv = *(const float4*)(sh + c);
  float4 scv = *(const float4*)(sc + c);
  float4 wv  = *(const float4*)(w3 + c);
  s4v ov;
  ov[0] = (short)f2bf(v.x * rms * wv.x * (1.f + scv.x) + shv.x);
  ov[1] = (short)f2bf(v.y * rms * wv.y * (1.f + scv.y) + shv.y);
  ov[2] = (short)f2bf(v.z * rms * wv.z * (1.f + scv.z) + shv.z);
  ov[3] = (short)f2bf(v.w * rms * wv.w * (1.f + scv.w) + shv.w);
  *(s4v*)(nm + (size_t)row * 1024 + c) = ov;
}

// ---------------------------------------------------------------------------
// host launcher
// ---------------------------------------------------------------------------
extern "C" void kernel_launch(void* const* d_in, const int* in_sizes, int n_in,
                              void* d_out, int out_size, void* d_ws, size_t ws_size,
                              hipStream_t stream)
{
  const float* x    = (const float*)d_in[0];
  const float* ts   = (const float*)d_in[1];
  const float* rope = (const float*)d_in[2];
  const float* adw  = (const float*)d_in[3];
  const float* adb  = (const float*)d_in[4];
  const float* wq   = (const float*)d_in[5];
  const float* wk   = (const float*)d_in[6];
  const float* wv   = (const float*)d_in[7];
  const float* wo   = (const float*)d_in[8];
  const float* qnw  = (const float*)d_in[9];
  const float* knw  = (const float*)d_in[10];
  const float* n3w  = (const float*)d_in[11];
  const float* f1w  = (const float*)d_in[12];
  const float* f1b  = (const float*)d_in[13];
  const float* f2w  = (const float*)d_in[14];
  const float* f2b  = (const float*)d_in[15];

  char* ws = (char*)d_ws;
  // bump-allocated ws layout (bytes); FF1 overlays QR..VT, NM overlays QKV,
  // ATTN overlays XM. total = 109,101,056 bytes.
  ushort_t* WQKV = (ushort_t*)(ws + 0);          //  6 MB  [3072][1024] bf16
  ushort_t* WO   = (ushort_t*)(ws + 6291456);    //  2 MB
  ushort_t* F1   = (ushort_t*)(ws + 8388608);    //  8 MB  [4096][1024]
  ushort_t* F2   = (ushort_t*)(ws + 16777216);   //  8 MB  [1024][4096]
  float*    EMB  = (float*)   (ws + 25165824);   //  48 KB [2][6144]
  float*    H    = (float*)   (ws + 25214976);   // 16 MB  [4096][1024] fp32
  ushort_t* XM   = (ushort_t*)(ws + 41992192);   //  8 MB  (later: ATTN)
  ushort_t* QKV  = (ushort_t*)(ws + 50380800);   // 24 MB  (later: NM)
  ushort_t* QR   = (ushort_t*)(ws + 75546624);   //  8 MB  (later: FF1 spans 32MB)
  ushort_t* KR   = (ushort_t*)(ws + 83935232);   //  8 MB
  ushort_t* VR   = (ushort_t*)(ws + 92323840);   //  8 MB
  ushort_t* VT   = (ushort_t*)(ws + 100712448);  //  8 MB
  ushort_t* ATTN = XM;
  ushort_t* NM   = QKV;
  ushort_t* FF1  = QR;

  convert_w<<<12288, 256, 0, stream>>>(wq, wk, wv, wo, f1w, f2w, WQKV, WO, F1, F2);
  adaln<<<1536, 256, 0, stream>>>(ts, adw, adb, EMB);
  ln_mod<<<4096, 256, 0, stream>>>(x, EMB, XM);
  gemm_bt<0><<<dim3(24, 32), 256, 0, stream>>>(XM, WQKV, 1024, 3072,
      QKV, nullptr, nullptr, nullptr, nullptr, 0);
  qkv_post<<<4096, 256, 0, stream>>>(QKV, rope, qnw, knw, QR, KR, VR);
  vtrans<<<1024, 256, 0, stream>>>(VR, VT);
  flash<<<1024, 256, 0, stream>>>(QR, KR, VT, ATTN);
  gemm_bt<1><<<dim3(8, 32), 256, 0, stream>>>(ATTN, WO, 1024, 1024,
      nullptr, H, nullptr, x, EMB, 2048);
  rms3_mod<<<4096, 256, 0, stream>>>(H, EMB, n3w, NM);
  gemm_bt<2><<<dim3(32, 32), 256, 0, stream>>>(NM, F1, 1024, 4096,
      FF1, nullptr, f1b, nullptr, nullptr, 0);
  gemm_bt<3><<<dim3(8, 32), 256, 0, stream>>>(FF1, F2, 4096, 1024,
      nullptr, (float*)d_out, f2b, H, EMB, 5120);
}

// Round 2
// 486.583 us; speedup vs baseline: 1.1604x; 1.1604x over previous
//
#include <hip/hip_runtime.h>
#include <cstdint>
#include <cstddef>

typedef unsigned short ushort_t;
typedef __attribute__((ext_vector_type(8))) short s8v;
typedef __attribute__((ext_vector_type(4))) short s4v;
typedef __attribute__((ext_vector_type(4))) float f4v;

#define MFMA16(a, b, c) __builtin_amdgcn_mfma_f32_16x16x32_bf16(a, b, c, 0, 0, 0)

__device__ __forceinline__ ushort_t f2bf(float f) {
  union { float f; unsigned u; } a; a.f = f;
  return (ushort_t)((a.u + 0x7fffu + ((a.u >> 16) & 1u)) >> 16);
}
__device__ __forceinline__ float bf2f(ushort_t h) {
  union { unsigned u; float f; } a; a.u = ((unsigned)h) << 16; return a.f;
}

// async global->LDS, 16B per lane; LDS dest is wave-uniform base + lane*16
__device__ __forceinline__ void gload16(const void* g, void* l) {
  __builtin_amdgcn_global_load_lds(
      (__attribute__((address_space(1))) void*)(uintptr_t)g,
      (__attribute__((address_space(3))) void*)(unsigned)(uintptr_t)l,
      16, 0, 0);
}

// ---------------------------------------------------------------------------
// 1) fp32 -> bf16 weight conversion. grid = 12288 blocks x 256 (1024 elem/blk)
// ---------------------------------------------------------------------------
__launch_bounds__(256)
__global__ void convert_w(const float* __restrict__ wq, const float* __restrict__ wk,
                          const float* __restrict__ wv, const float* __restrict__ wo,
                          const float* __restrict__ f1, const float* __restrict__ f2,
                          ushort_t* __restrict__ dqkv, ushort_t* __restrict__ dwo,
                          ushort_t* __restrict__ df1, ushort_t* __restrict__ df2)
{
  const int blk = blockIdx.x;
  const float* src; ushort_t* dst; int off;
  if      (blk < 1024) { src = wq; dst = dqkv;            off = blk; }
  else if (blk < 2048) { src = wk; dst = dqkv + 1048576;  off = blk - 1024; }
  else if (blk < 3072) { src = wv; dst = dqkv + 2097152;  off = blk - 2048; }
  else if (blk < 4096) { src = wo; dst = dwo;             off = blk - 3072; }
  else if (blk < 8192) { src = f1; dst = df1;             off = blk - 4096; }
  else                 { src = f2; dst = df2;             off = blk - 8192; }
  const int idx = off * 1024 + threadIdx.x * 4;
  float4 v = *(const float4*)(src + idx);
  s4v o;
  o[0] = (short)f2bf(v.x); o[1] = (short)f2bf(v.y);
  o[2] = (short)f2bf(v.z); o[3] = (short)f2bf(v.w);
  *(s4v*)(dst + idx) = o;
}

// ---------------------------------------------------------------------------
// 2) adaln: emb[b][j] = sum_d silu(ts[b][d]) * w[j][d] + bias[j]
// ---------------------------------------------------------------------------
__launch_bounds__(256)
__global__ void adaln(const float* __restrict__ ts, const float* __restrict__ w,
                      const float* __restrict__ bias, float* __restrict__ emb)
{
  const int j = blockIdx.x * 4 + (threadIdx.x >> 6);
  const int lane = threadIdx.x & 63;
  const float* wr = w + (size_t)j * 1024;
  float s0 = 0.f, s1 = 0.f;
  for (int i = lane; i < 1024; i += 64) {
    const float wv = wr[i];
    const float t0 = ts[i], t1 = ts[1024 + i];
    s0 += wv * (t0 / (1.f + __expf(-t0)));
    s1 += wv * (t1 / (1.f + __expf(-t1)));
  }
  #pragma unroll
  for (int m = 32; m; m >>= 1) { s0 += __shfl_down(s0, m); s1 += __shfl_down(s1, m); }
  if (!lane) { emb[j] = s0 + bias[j]; emb[6144 + j] = s1 + bias[j]; }
}

// ---------------------------------------------------------------------------
// 3) LayerNorm + msa modulation -> xm bf16. one block per row.
// ---------------------------------------------------------------------------
__launch_bounds__(256)
__global__ void ln_mod(const float* __restrict__ x, const float* __restrict__ emb,
                       ushort_t* __restrict__ xm)
{
  const int row = blockIdx.x, b = row >> 11, tid = threadIdx.x;
  const float* xr = x + (size_t)row * 1024;
  const int c = tid * 4;
  float4 v = *(const float4*)(xr + c);
  float s  = v.x + v.y + v.z + v.w;
  float s2 = v.x*v.x + v.y*v.y + v.z*v.z + v.w*v.w;
  #pragma unroll
  for (int m = 32; m; m >>= 1) { s += __shfl_down(s, m); s2 += __shfl_down(s2, m); }
  __shared__ float red[8];
  const int wave = tid >> 6, lane = tid & 63;
  if (!lane) { red[wave] = s; red[4 + wave] = s2; }
  __syncthreads();
  const float mu = (red[0] + red[1] + red[2] + red[3]) * (1.f / 1024.f);
  const float ms = (red[4] + red[5] + red[6] + red[7]) * (1.f / 1024.f);
  const float rstd = rsqrtf(ms - mu * mu + 1e-6f);
  const float* sh = emb + b * 6144;
  const float* sc = emb + b * 6144 + 1024;
  float4 shv = *(const float4*)(sh + c);
  float4 scv = *(const float4*)(sc + c);
  s4v ov;
  ov[0] = (short)f2bf((v.x - mu) * rstd * (1.f + scv.x) + shv.x);
  ov[1] = (short)f2bf((v.y - mu) * rstd * (1.f + scv.y) + shv.y);
  ov[2] = (short)f2bf((v.z - mu) * rstd * (1.f + scv.z) + shv.z);
  ov[3] = (short)f2bf((v.w - mu) * rstd * (1.f + scv.w) + shv.w);
  *(s4v*)(xm + (size_t)row * 1024 + c) = ov;
}

// ---------------------------------------------------------------------------
// 4) bf16 B^T GEMM, m97 structure (unchanged from round 1).
// ---------------------------------------------------------------------------
template<int EPI>
__launch_bounds__(256)
__global__ void gemm_bt(const ushort_t* __restrict__ A, const ushort_t* __restrict__ Bw,
                        int K, int N,
                        ushort_t* __restrict__ outb, float* __restrict__ outf,
                        const float* __restrict__ bias, const float* __restrict__ resid,
                        const float* __restrict__ emb, int gate_off)
{
  __shared__ ushort_t As[128 * 32];
  __shared__ ushort_t Bs[128 * 32];
  const int tid = threadIdx.x;
  const int wave = tid >> 6, lane = tid & 63;
  const int quad = lane >> 4, r = lane & 15;
  const int m0 = blockIdx.y * 128, n0 = blockIdx.x * 128;
  const int wm = (wave >> 1) * 64, wn = (wave & 1) * 64;

  const int srow = wave * 16 + (lane >> 2);
  const int scol = (lane & 3) * 8;
  const ushort_t* ag = A  + (size_t)(m0 + srow) * K + scol;
  const ushort_t* bg = Bw + (size_t)(n0 + srow) * K + scol;
  const size_t rowK64 = (size_t)64 * K;
  ushort_t* as0 = As + wave * 512;
  ushort_t* as1 = As + 2048 + wave * 512;
  ushort_t* bs0 = Bs + wave * 512;
  ushort_t* bs1 = Bs + 2048 + wave * 512;

  f4v acc[4][4] = {};

  for (int k0 = 0; k0 < K; k0 += 32) {
    __syncthreads();
    gload16(ag,          as0);
    gload16(ag + rowK64, as1);
    gload16(bg,          bs0);
    gload16(bg + rowK64, bs1);
    ag += 32; bg += 32;
    __syncthreads();
    s8v af[4], bf[4];
    #pragma unroll
    for (int i = 0; i < 4; i++)
      af[i] = *(const s8v*)(As + (wm + i * 16 + r) * 32 + quad * 8);
    #pragma unroll
    for (int i = 0; i < 4; i++)
      bf[i] = *(const s8v*)(Bs + (wn + i * 16 + r) * 32 + quad * 8);
    #pragma unroll
    for (int i = 0; i < 4; i++)
      #pragma unroll
      for (int j = 0; j < 4; j++)
        acc[i][j] = MFMA16(af[i], bf[j], acc[i][j]);
  }

  #pragma unroll
  for (int i = 0; i < 4; i++) {
    const int row = m0 + wm + i * 16 + quad * 4;
    #pragma unroll
    for (int j = 0; j < 4; j++) {
      const int col = n0 + wn + j * 16 + r;
      #pragma unroll
      for (int rr = 0; rr < 4; rr++) {
        float v = acc[i][j][rr];
        const int rw = row + rr;
        const size_t idx = (size_t)rw * N + col;
        if (EPI == 0) {
          outb[idx] = f2bf(v);
        } else if (EPI == 1) {
          const int b = rw >> 11;
          outf[idx] = resid[idx] + emb[b * 6144 + gate_off + col] * v;
        } else if (EPI == 2) {
          v += bias[col];
          const float u = 0.7978845608028654f * (v + 0.044715f * v * v * v);
          const float e = __expf(2.f * u);
          const float th = 1.f - 2.f / (e + 1.f);
          outb[idx] = f2bf(0.5f * v * (1.f + th));
        } else {
          const int b = rw >> 11;
          outf[idx] = resid[idx] + emb[b * 6144 + gate_off + col] * (v + bias[col]);
        }
      }
    }
  }
}

// ---------------------------------------------------------------------------
// 5) QKV post: RMSNorm + RoPE + layout.
//    Q: [B,H,S,HD] bf16, pre-scaled by 0.125*log2(e) (flash uses exp2).
//    K: [B,H,S,HD] bf16 with 16B chunks XOR-swizzled (chunk ^= s&7) so flash's
//       global_load_lds lands pre-swizzled (bank-conflict-free b128 reads).
// ---------------------------------------------------------------------------
__launch_bounds__(256)
__global__ void qkv_post(const ushort_t* __restrict__ qkv, const float* __restrict__ rope,
                         const float* __restrict__ qw, const float* __restrict__ kw,
                         ushort_t* __restrict__ q_r, ushort_t* __restrict__ k_r,
                         ushort_t* __restrict__ v_r)
{
  const int row = blockIdx.x, b = row >> 11, s = row & 2047, tid = threadIdx.x;
  const ushort_t* base = qkv + (size_t)row * 3072;
  const int c = tid * 4;
  s4v qv = *(const s4v*)(base + c);
  s4v kv = *(const s4v*)(base + 1024 + c);
  s4v vv = *(const s4v*)(base + 2048 + c);
  float qf[4], kf[4]; float sq = 0.f, sk = 0.f;
  #pragma unroll
  for (int i = 0; i < 4; i++) {
    qf[i] = bf2f((ushort_t)qv[i]); kf[i] = bf2f((ushort_t)kv[i]);
    sq += qf[i] * qf[i]; sk += kf[i] * kf[i];
  }
  #pragma unroll
  for (int m = 32; m; m >>= 1) { sq += __shfl_down(sq, m); sk += __shfl_down(sk, m); }
  __shared__ float red[8];
  const int wave = tid >> 6, lane = tid & 63;
  if (!lane) { red[wave] = sq; red[4 + wave] = sk; }
  __syncthreads();
  const float rq = rsqrtf((red[0]+red[1]+red[2]+red[3]) * (1.f/1024.f) + 1e-6f)
                   * 0.18033688011112042f;  // fold 0.125*log2(e) into Q
  const float rk = rsqrtf((red[4]+red[5]+red[6]+red[7]) * (1.f/1024.f) + 1e-6f);

  const int h = c >> 6, d = c & 63;
  const float* rp = rope + ((size_t)s * 64 + d) * 2;
  float4 r01 = *(const float4*)(rp);
  float4 r23 = *(const float4*)(rp + 4);
  const float q0 = qf[0]*rq*qw[c], q1 = qf[1]*rq*qw[c+1];
  const float q2 = qf[2]*rq*qw[c+2], q3 = qf[3]*rq*qw[c+3];
  const float k0 = kf[0]*rk*kw[c], k1 = kf[1]*rk*kw[c+1];
  const float k2 = kf[2]*rk*kw[c+2], k3 = kf[3]*rk*kw[c+3];
  s4v qo, ko;
  qo[0] = (short)f2bf(q0 * r01.x - q1 * r01.y);
  qo[1] = (short)f2bf(q1 * r01.z + q0 * r01.w);
  qo[2] = (short)f2bf(q2 * r23.x - q3 * r23.y);
  qo[3] = (short)f2bf(q3 * r23.z + q2 * r23.w);
  ko[0] = (short)f2bf(k0 * r01.x - k1 * r01.y);
  ko[1] = (short)f2bf(k1 * r01.z + k0 * r01.w);
  ko[2] = (short)f2bf(k2 * r23.x - k3 * r23.y);
  ko[3] = (short)f2bf(k3 * r23.z + k2 * r23.w);
  const size_t rowbase = ((size_t)(b * 16 + h) * 2048 + s) * 64;
  const int d_s = (((d >> 3) ^ (s & 7)) << 3) | (d & 7);   // K chunk swizzle
  *(s4v*)(q_r + rowbase + d) = qo;
  *(s4v*)(k_r + rowbase + d_s) = ko;
  *(s4v*)(v_r + rowbase + d) = vv;
}

// ---------------------------------------------------------------------------
// 6) V transpose: [B,H,S,HD] -> [B,H,HD,S], 16B chunks XOR-swizzled within
//    each 64-key group (chunk ^= d&7) for flash's b128 LDS reads.
// ---------------------------------------------------------------------------
__launch_bounds__(256)
__global__ void vtrans(const ushort_t* __restrict__ v_r, ushort_t* __restrict__ v_t)
{
  const int bh = blockIdx.x >> 5, st = blockIdx.x & 31;
  const int s0 = st * 64;
  __shared__ ushort_t tile[64 * 72];
  const int tid = threadIdx.x;
  #pragma unroll
  for (int rep = 0; rep < 2; rep++) {
    const int idx = rep * 256 + tid;
    const int sr = idx >> 3, dc = (idx & 7) << 3;
    s8v val = *(const s8v*)(v_r + ((size_t)bh * 2048 + s0 + sr) * 64 + dc);
    *(s8v*)(tile + sr * 72 + dc) = val;
  }
  __syncthreads();
  #pragma unroll
  for (int rep = 0; rep < 2; rep++) {
    const int idx = rep * 256 + tid;
    const int d = idx >> 3;
    const int scs = (((idx & 7) ^ (d & 7)) << 3);   // swizzled key-chunk
    s8v val;
    const int sc = (idx & 7) << 3;
    #pragma unroll
    for (int j = 0; j < 8; j++) val[j] = (short)tile[(sc + j) * 72 + d];
    *(s8v*)(v_t + ((size_t)bh * 64 + d) * 2048 + s0 + scs) = val;
  }
}

// ---------------------------------------------------------------------------
// 7) Flash attention v2. block = (b,h, 64 q); wave = 16 q; 64-key tiles.
//    S^T = K*Q^T  (row=key, col=q)  -> softmax in-lane + 2 shfl_xor
//    P^T packs 4 keys/lane -> ds_write_b64 into XOR-swizzled Psh
//    O = P*V via Psh(A) x Vsh(B).  K/V staged with global_load_lds(16B),
//    layouts pre-swizzled by producers.
// ---------------------------------------------------------------------------
__launch_bounds__(256)
__global__ void flash(const ushort_t* __restrict__ q_r, const ushort_t* __restrict__ k_r,
                      const ushort_t* __restrict__ v_t, ushort_t* __restrict__ attn)
{
  __shared__ ushort_t Ksh[64 * 64];      // [key][d], chunks ^(key&7)
  __shared__ ushort_t Vsh[64 * 64];      // [d][key], chunks ^(d&7)
  __shared__ ushort_t Psh[4][16 * 64];   // per-wave [q][key], chunks ^(q&7)
  const int bh = blockIdx.x >> 5, qb = blockIdx.x & 31;
  const int tid = threadIdx.x, wave = tid >> 6, lane = tid & 63;
  const int quad = lane >> 4, r = lane & 15;
  const int rx = r & 7;
  const int q0 = qb * 64 + wave * 16;
  const size_t bhS = (size_t)bh * 2048;

  s8v aq0 = *(const s8v*)(q_r + (bhS + q0 + r) * 64 + quad * 8);
  s8v aq1 = *(const s8v*)(q_r + (bhS + q0 + r) * 64 + 32 + quad * 8);

  f4v o[4] = {};
  float mi = -1e30f, li = 0.f;

  // staging pointers (wave covers 2 KiB of each of K and V per 64-key tile)
  const ushort_t* kg = k_r + bhS * 64 + wave * 1024 + lane * 8;
  const ushort_t* vg0 = v_t + ((size_t)bh * 64 + wave * 16 + (lane >> 3)) * 2048
                        + (lane & 7) * 8;
  const ushort_t* vg1 = vg0 + (size_t)8 * 2048;
  ushort_t* kl0 = Ksh + wave * 1024;
  ushort_t* kl1 = Ksh + wave * 1024 + 512;
  ushort_t* vl0 = Vsh + wave * 1024;
  ushort_t* vl1 = Vsh + wave * 1024 + 512;
  ushort_t* pw = &Psh[wave][0];

  for (int kb = 0; kb < 2048; kb += 64) {
    __syncthreads();
    gload16(kg,        kl0);
    gload16(kg + 512,  kl1);
    gload16(vg0 + kb,  vl0);
    gload16(vg1 + kb,  vl1);
    kg += 64 * 64;
    __syncthreads();

    // S^T: 16 keys x 16 q per tile, 4 tiles
    f4v st[4];
    #pragma unroll
    for (int t = 0; t < 4; t++) {
      const ushort_t* krow = Ksh + (t * 16 + r) * 64;
      s8v k0 = *(const s8v*)(krow + (((quad) ^ rx) << 3));
      s8v k1 = *(const s8v*)(krow + (((4 + quad) ^ rx) << 3));
      f4v z = {};
      z = MFMA16(k0, aq0, z);
      z = MFMA16(k1, aq1, z);
      st[t] = z;
    }

    // online softmax for q=r over this lane's 16 keys, then across quads
    float mloc = st[0][0];
    #pragma unroll
    for (int t = 0; t < 4; t++)
      #pragma unroll
      for (int rr = 0; rr < 4; rr++) mloc = fmaxf(mloc, st[t][rr]);
    mloc = fmaxf(mloc, __shfl_xor(mloc, 16));
    mloc = fmaxf(mloc, __shfl_xor(mloc, 32));
    const float mn = fmaxf(mi, mloc);
    const float al = exp2f(mi - mn);
    float ls = 0.f;
    float p[4][4];
    #pragma unroll
    for (int t = 0; t < 4; t++)
      #pragma unroll
      for (int rr = 0; rr < 4; rr++) {
        p[t][rr] = exp2f(st[t][rr] - mn);
        ls += p[t][rr];
      }
    ls += __shfl_xor(ls, 16);
    ls += __shfl_xor(ls, 32);
    li = al * li + ls;
    mi = mn;

    // write P^T -> Psh[q][key] (4 consecutive keys per b64 write, swizzled)
    #pragma unroll
    for (int t = 0; t < 4; t++) {
      s4v pb;
      pb[0] = (short)f2bf(p[t][0]); pb[1] = (short)f2bf(p[t][1]);
      pb[2] = (short)f2bf(p[t][2]); pb[3] = (short)f2bf(p[t][3]);
      const int idx = r * 64 + (((((t << 1) | (quad >> 1))) ^ rx) << 3) + (quad & 1) * 4;
      *(s4v*)(pw + idx) = pb;
    }

    // rescale O rows (row q = quad*4+rr needs alpha from lane quad*4+rr)
    float alo[4];
    #pragma unroll
    for (int rr = 0; rr < 4; rr++) alo[rr] = __shfl(al, quad * 4 + rr);
    #pragma unroll
    for (int nt = 0; nt < 4; nt++)
      #pragma unroll
      for (int rr = 0; rr < 4; rr++) o[nt][rr] *= alo[rr];

    asm volatile("s_waitcnt lgkmcnt(0)" ::: "memory");  // P write -> read, same wave

    // O += P * V
    #pragma unroll
    for (int kc = 0; kc < 2; kc++) {
      s8v ap = *(const s8v*)(pw + r * 64 + ((((kc << 2) | quad) ^ rx) << 3));
      #pragma unroll
      for (int nt = 0; nt < 4; nt++) {
        s8v bv = *(const s8v*)(Vsh + (nt * 16 + r) * 64 + ((((kc << 2) | quad) ^ rx) << 3));
        o[nt] = MFMA16(ap, bv, o[nt]);
      }
    }
  }

  const int h = bh & 15, b = bh >> 4;
  const float linv = 1.f / li;
  #pragma unroll
  for (int rr = 0; rr < 4; rr++) {
    const float inv = __shfl(linv, quad * 4 + rr);
    const size_t orow = ((size_t)(b * 2048 + q0 + quad * 4 + rr)) * 1024 + h * 64;
    #pragma unroll
    for (int nt = 0; nt < 4; nt++)
      attn[orow + nt * 16 + r] = f2bf(o[nt][rr] * inv);
  }
}

// ---------------------------------------------------------------------------
// 8) RMSNorm3 + mlp modulation -> nm bf16
// ---------------------------------------------------------------------------
__launch_bounds__(256)
__global__ void rms3_mod(const float* __restrict__ h, const float* __restrict__ emb,
                         const float* __restrict__ w3, ushort_t* __restrict__ nm)
{
  const int row = blockIdx.x, b = row >> 11, tid = threadIdx.x;
  const float* hr = h + (size_t)row * 1024;
  const int c = tid * 4;
  float4 v = *(const float4*)(hr + c);
  float s2 = v.x*v.x + v.y*v.y + v.z*v.z + v.w*v.w;
  #pragma unroll
  for (int m = 32; m; m >>= 1) s2 += __shfl_down(s2, m);
  __shared__ float red[4];
  const int wave = tid >> 6, lane = tid & 63;
  if (!lane) red[wave] = s2;
  __syncthreads();
  const float rms = rsqrtf((red[0] + red[1] + red[2] + red[3]) * (1.f / 1024.f) + 1e-6f);
  const float* sh = emb + b * 6144 + 3072;
  const float* sc = emb + b * 6144 + 4096;
  float4 shv = *(const float4*)(sh + c);
  float4 scv = *(const float4*)(sc + c);
  float4 wv  = *(const float4*)(w3 + c);
  s4v ov;
  ov[0] = (short)f2bf(v.x * rms * wv.x * (1.f + scv.x) + shv.x);
  ov[1] = (short)f2bf(v.y * rms * wv.y * (1.f + scv.y) + shv.y);
  ov[2] = (short)f2bf(v.z * rms * wv.z * (1.f + scv.z) + shv.z);
  ov[3] = (short)f2bf(v.w * rms * wv.w * (1.f + scv.w) + shv.w);
  *(s4v*)(nm + (size_t)row * 1024 + c) = ov;
}

// ---------------------------------------------------------------------------
// host launcher
// ---------------------------------------------------------------------------
extern "C" void kernel_launch(void* const* d_in, const int* in_sizes, int n_in,
                              void* d_out, int out_size, void* d_ws, size_t ws_size,
                              hipStream_t stream)
{
  const float* x    = (const float*)d_in[0];
  const float* ts   = (const float*)d_in[1];
  const float* rope = (const float*)d_in[2];
  const float* adw  = (const float*)d_in[3];
  const float* adb  = (const float*)d_in[4];
  const float* wq   = (const float*)d_in[5];
  const float* wk   = (const float*)d_in[6];
  const float* wv   = (const float*)d_in[7];
  const float* wo   = (const float*)d_in[8];
  const float* qnw  = (const float*)d_in[9];
  const float* knw  = (const float*)d_in[10];
  const float* n3w  = (const float*)d_in[11];
  const float* f1w  = (const float*)d_in[12];
  const float* f1b  = (const float*)d_in[13];
  const float* f2w  = (const float*)d_in[14];
  const float* f2b  = (const float*)d_in[15];

  char* ws = (char*)d_ws;
  ushort_t* WQKV = (ushort_t*)(ws + 0);          //  6 MB
  ushort_t* WO   = (ushort_t*)(ws + 6291456);    //  2 MB
  ushort_t* F1   = (ushort_t*)(ws + 8388608);    //  8 MB
  ushort_t* F2   = (ushort_t*)(ws + 16777216);   //  8 MB
  float*    EMB  = (float*)   (ws + 25165824);   //  48 KB
  float*    H    = (float*)   (ws + 25214976);   // 16 MB
  ushort_t* XM   = (ushort_t*)(ws + 41992192);   //  8 MB  (later: ATTN)
  ushort_t* QKV  = (ushort_t*)(ws + 50380800);   // 24 MB  (later: NM)
  ushort_t* QR   = (ushort_t*)(ws + 75546624);   //  8 MB  (later: FF1 spans 32MB)
  ushort_t* KR   = (ushort_t*)(ws + 83935232);   //  8 MB
  ushort_t* VR   = (ushort_t*)(ws + 92323840);   //  8 MB
  ushort_t* VT   = (ushort_t*)(ws + 100712448);  //  8 MB
  ushort_t* ATTN = XM;
  ushort_t* NM   = QKV;
  ushort_t* FF1  = QR;

  convert_w<<<12288, 256, 0, stream>>>(wq, wk, wv, wo, f1w, f2w, WQKV, WO, F1, F2);
  adaln<<<1536, 256, 0, stream>>>(ts, adw, adb, EMB);
  ln_mod<<<4096, 256, 0, stream>>>(x, EMB, XM);
  gemm_bt<0><<<dim3(24, 32), 256, 0, stream>>>(XM, WQKV, 1024, 3072,
      QKV, nullptr, nullptr, nullptr, nullptr, 0);
  qkv_post<<<4096, 256, 0, stream>>>(QKV, rope, qnw, knw, QR, KR, VR);
  vtrans<<<1024, 256, 0, stream>>>(VR, VT);
  flash<<<1024, 256, 0, stream>>>(QR, KR, VT, ATTN);
  gemm_bt<1><<<dim3(8, 32), 256, 0, stream>>>(ATTN, WO, 1024, 1024,
      nullptr, H, nullptr, x, EMB, 2048);
  rms3_mod<<<4096, 256, 0, stream>>>(H, EMB, n3w, NM);
  gemm_bt<2><<<dim3(32, 32), 256, 0, stream>>>(NM, F1, 1024, 4096,
      FF1, nullptr, f1b, nullptr, nullptr, 0);
  gemm_bt<3><<<dim3(8, 32), 256, 0, stream>>>(FF1, F2, 4096, 1024,
      nullptr, (float*)d_out, f2b, H, EMB, 5120);
}

// Round 3
// 441.879 us; speedup vs baseline: 1.2778x; 1.1012x over previous
//
#include <hip/hip_runtime.h>
#include <cstdint>
#include <cstddef>

typedef unsigned short ushort_t;
typedef __attribute__((ext_vector_type(8))) short s8v;
typedef __attribute__((ext_vector_type(4))) short s4v;
typedef __attribute__((ext_vector_type(4))) float f4v;

#define MFMA16(a, b, c) __builtin_amdgcn_mfma_f32_16x16x32_bf16(a, b, c, 0, 0, 0)

__device__ __forceinline__ ushort_t f2bf(float f) {
  union { float f; unsigned u; } a; a.f = f;
  return (ushort_t)((a.u + 0x7fffu + ((a.u >> 16) & 1u)) >> 16);
}
__device__ __forceinline__ float bf2f(ushort_t h) {
  union { unsigned u; float f; } a; a.u = ((unsigned)h) << 16; return a.f;
}

// async global->LDS, 16B per lane; LDS dest is wave-uniform base + lane*16
__device__ __forceinline__ void gload16(const void* g, void* l) {
  __builtin_amdgcn_global_load_lds(
      (__attribute__((address_space(1))) void*)(uintptr_t)g,
      (__attribute__((address_space(3))) void*)(unsigned)(uintptr_t)l,
      16, 0, 0);
}

// ---------------------------------------------------------------------------
// 1) fp32 -> bf16 weight conversion. grid = 12288 blocks x 256 (1024 elem/blk)
// ---------------------------------------------------------------------------
__launch_bounds__(256)
__global__ void convert_w(const float* __restrict__ wq, const float* __restrict__ wk,
                          const float* __restrict__ wv, const float* __restrict__ wo,
                          const float* __restrict__ f1, const float* __restrict__ f2,
                          ushort_t* __restrict__ dqkv, ushort_t* __restrict__ dwo,
                          ushort_t* __restrict__ df1, ushort_t* __restrict__ df2)
{
  const int blk = blockIdx.x;
  const float* src; ushort_t* dst; int off;
  if      (blk < 1024) { src = wq; dst = dqkv;            off = blk; }
  else if (blk < 2048) { src = wk; dst = dqkv + 1048576;  off = blk - 1024; }
  else if (blk < 3072) { src = wv; dst = dqkv + 2097152;  off = blk - 2048; }
  else if (blk < 4096) { src = wo; dst = dwo;             off = blk - 3072; }
  else if (blk < 8192) { src = f1; dst = df1;             off = blk - 4096; }
  else                 { src = f2; dst = df2;             off = blk - 8192; }
  const int idx = off * 1024 + threadIdx.x * 4;
  float4 v = *(const float4*)(src + idx);
  s4v o;
  o[0] = (short)f2bf(v.x); o[1] = (short)f2bf(v.y);
  o[2] = (short)f2bf(v.z); o[3] = (short)f2bf(v.w);
  *(s4v*)(dst + idx) = o;
}

// ---------------------------------------------------------------------------
// 2) adaln: emb[b][j] = sum_d silu(ts[b][d]) * w[j][d] + bias[j]
// ---------------------------------------------------------------------------
__launch_bounds__(256)
__global__ void adaln(const float* __restrict__ ts, const float* __restrict__ w,
                      const float* __restrict__ bias, float* __restrict__ emb)
{
  const int j = blockIdx.x * 4 + (threadIdx.x >> 6);
  const int lane = threadIdx.x & 63;
  const float* wr = w + (size_t)j * 1024;
  float s0 = 0.f, s1 = 0.f;
  for (int i = lane; i < 1024; i += 64) {
    const float wv = wr[i];
    const float t0 = ts[i], t1 = ts[1024 + i];
    s0 += wv * (t0 / (1.f + __expf(-t0)));
    s1 += wv * (t1 / (1.f + __expf(-t1)));
  }
  #pragma unroll
  for (int m = 32; m; m >>= 1) { s0 += __shfl_down(s0, m); s1 += __shfl_down(s1, m); }
  if (!lane) { emb[j] = s0 + bias[j]; emb[6144 + j] = s1 + bias[j]; }
}

// ---------------------------------------------------------------------------
// 3) LayerNorm + msa modulation -> xm bf16. one block per row.
// ---------------------------------------------------------------------------
__launch_bounds__(256)
__global__ void ln_mod(const float* __restrict__ x, const float* __restrict__ emb,
                       ushort_t* __restrict__ xm)
{
  const int row = blockIdx.x, b = row >> 11, tid = threadIdx.x;
  const float* xr = x + (size_t)row * 1024;
  const int c = tid * 4;
  float4 v = *(const float4*)(xr + c);
  float s  = v.x + v.y + v.z + v.w;
  float s2 = v.x*v.x + v.y*v.y + v.z*v.z + v.w*v.w;
  #pragma unroll
  for (int m = 32; m; m >>= 1) { s += __shfl_down(s, m); s2 += __shfl_down(s2, m); }
  __shared__ float red[8];
  const int wave = tid >> 6, lane = tid & 63;
  if (!lane) { red[wave] = s; red[4 + wave] = s2; }
  __syncthreads();
  const float mu = (red[0] + red[1] + red[2] + red[3]) * (1.f / 1024.f);
  const float ms = (red[4] + red[5] + red[6] + red[7]) * (1.f / 1024.f);
  const float rstd = rsqrtf(ms - mu * mu + 1e-6f);
  const float* sh = emb + b * 6144;
  const float* sc = emb + b * 6144 + 1024;
  float4 shv = *(const float4*)(sh + c);
  float4 scv = *(const float4*)(sc + c);
  s4v ov;
  ov[0] = (short)f2bf((v.x - mu) * rstd * (1.f + scv.x) + shv.x);
  ov[1] = (short)f2bf((v.y - mu) * rstd * (1.f + scv.y) + shv.y);
  ov[2] = (short)f2bf((v.z - mu) * rstd * (1.f + scv.z) + shv.z);
  ov[3] = (short)f2bf((v.w - mu) * rstd * (1.f + scv.w) + shv.w);
  *(s4v*)(xm + (size_t)row * 1024 + c) = ov;
}

// ---------------------------------------------------------------------------
// 4) bf16 B^T GEMM, double-buffered LDS (1 barrier/iter, prefetch overlaps
//    compute). Tile 128 x TN, BK=32. TN=128: 4 waves at 64x64 (16 MFMA/iter);
//    TN=64: 4 waves at 64x32 (8 MFMA/iter) -> 2x grid for N=1024 GEMMs.
//    EPI: 0 = bf16 store, 1 = h = x + g_msa*o (fp32), 2 = bias+gelu (bf16),
//         3 = out = h + g_mlp*(v+bias) (fp32)
// ---------------------------------------------------------------------------
template<int EPI, int TN>
__launch_bounds__(256)
__global__ void gemm_bt(const ushort_t* __restrict__ A, const ushort_t* __restrict__ Bw,
                        int K, int N,
                        ushort_t* __restrict__ outb, float* __restrict__ outf,
                        const float* __restrict__ bias, const float* __restrict__ resid,
                        const float* __restrict__ emb, int gate_off)
{
  constexpr int JN = TN / 32;            // 4 or 2 n-frags per wave
  constexpr int BUFB = TN * 32;          // B buffer elems
  __shared__ ushort_t As[2 * 128 * 32];
  __shared__ ushort_t Bs[2 * BUFB];
  const int tid = threadIdx.x;
  const int wave = tid >> 6, lane = tid & 63;
  const int quad = lane >> 4, r = lane & 15;
  const int m0 = blockIdx.y * 128, n0 = blockIdx.x * TN;
  const int wm = (wave >> 1) * 64, wn = (wave & 1) * (TN / 2);

  // staging: wave w covers rows w*16..w*16+15 (and +64), lane covers 16B of k
  const int srow = wave * 16 + (lane >> 2);
  const int scol = (lane & 3) * 8;
  const ushort_t* ag = A  + (size_t)(m0 + srow) * K + scol;
  const ushort_t* bg = Bw + (size_t)(n0 + srow) * K + scol;
  const size_t rowK64 = (size_t)64 * K;

  f4v acc[4][JN] = {};

  // prologue: stage tile 0 into buffer 0
  {
    ushort_t* as = As + wave * 512;
    ushort_t* bs = Bs + wave * 512;
    gload16(ag,          as);
    gload16(ag + rowK64, as + 2048);
    gload16(bg,          bs);
    if (TN == 128) gload16(bg + rowK64, bs + 2048);
    ag += 32; bg += 32;
  }

  const int nIter = K >> 5;
  int cur = 0;
  for (int it = 0; it < nIter - 1; it++) {
    __syncthreads();                     // drains vmcnt: buf[cur] ready; buf[cur^1] reads done
    // prefetch tile it+1 into the alternate buffer (overlaps MFMA below)
    {
      ushort_t* as = As + (cur ^ 1) * 4096 + wave * 512;
      ushort_t* bs = Bs + (cur ^ 1) * BUFB + wave * 512;
      gload16(ag,          as);
      gload16(ag + rowK64, as + 2048);
      gload16(bg,          bs);
      if (TN == 128) gload16(bg + rowK64, bs + 2048);
      ag += 32; bg += 32;
    }
    // compute on buf[cur]
    const ushort_t* ab = As + cur * 4096;
    const ushort_t* bb = Bs + cur * BUFB;
    s8v af[4], bf[JN];
    #pragma unroll
    for (int i = 0; i < 4; i++)
      af[i] = *(const s8v*)(ab + (wm + i * 16 + r) * 32 + quad * 8);
    #pragma unroll
    for (int j = 0; j < JN; j++)
      bf[j] = *(const s8v*)(bb + (wn + j * 16 + r) * 32 + quad * 8);
    #pragma unroll
    for (int i = 0; i < 4; i++)
      #pragma unroll
      for (int j = 0; j < JN; j++)
        acc[i][j] = MFMA16(af[i], bf[j], acc[i][j]);
    cur ^= 1;
  }
  // last tile
  __syncthreads();
  {
    const ushort_t* ab = As + cur * 4096;
    const ushort_t* bb = Bs + cur * BUFB;
    s8v af[4], bf[JN];
    #pragma unroll
    for (int i = 0; i < 4; i++)
      af[i] = *(const s8v*)(ab + (wm + i * 16 + r) * 32 + quad * 8);
    #pragma unroll
    for (int j = 0; j < JN; j++)
      bf[j] = *(const s8v*)(bb + (wn + j * 16 + r) * 32 + quad * 8);
    #pragma unroll
    for (int i = 0; i < 4; i++)
      #pragma unroll
      for (int j = 0; j < JN; j++)
        acc[i][j] = MFMA16(af[i], bf[j], acc[i][j]);
  }

  #pragma unroll
  for (int i = 0; i < 4; i++) {
    const int row = m0 + wm + i * 16 + quad * 4;
    #pragma unroll
    for (int j = 0; j < JN; j++) {
      const int col = n0 + wn + j * 16 + r;
      #pragma unroll
      for (int rr = 0; rr < 4; rr++) {
        float v = acc[i][j][rr];
        const int rw = row + rr;
        const size_t idx = (size_t)rw * N + col;
        if (EPI == 0) {
          outb[idx] = f2bf(v);
        } else if (EPI == 1) {
          const int b = rw >> 11;
          outf[idx] = resid[idx] + emb[b * 6144 + gate_off + col] * v;
        } else if (EPI == 2) {
          v += bias[col];
          const float u = 0.7978845608028654f * (v + 0.044715f * v * v * v);
          const float e = __expf(2.f * u);
          const float th = 1.f - 2.f / (e + 1.f);
          outb[idx] = f2bf(0.5f * v * (1.f + th));
        } else {
          const int b = rw >> 11;
          outf[idx] = resid[idx] + emb[b * 6144 + gate_off + col] * (v + bias[col]);
        }
      }
    }
  }
}

// ---------------------------------------------------------------------------
// 5) QKV post: RMSNorm + RoPE + layout.
//    Q: [B,H,S,HD] bf16, pre-scaled by 0.125*log2(e) (flash uses exp2).
//    K: [B,H,S,HD] bf16 with 16B chunks XOR-swizzled (chunk ^= s&7) so flash's
//       global_load_lds lands pre-swizzled (bank-conflict-free b128 reads).
// ---------------------------------------------------------------------------
__launch_bounds__(256)
__global__ void qkv_post(const ushort_t* __restrict__ qkv, const float* __restrict__ rope,
                         const float* __restrict__ qw, const float* __restrict__ kw,
                         ushort_t* __restrict__ q_r, ushort_t* __restrict__ k_r,
                         ushort_t* __restrict__ v_r)
{
  const int row = blockIdx.x, b = row >> 11, s = row & 2047, tid = threadIdx.x;
  const ushort_t* base = qkv + (size_t)row * 3072;
  const int c = tid * 4;
  s4v qv = *(const s4v*)(base + c);
  s4v kv = *(const s4v*)(base + 1024 + c);
  s4v vv = *(const s4v*)(base + 2048 + c);
  float qf[4], kf[4]; float sq = 0.f, sk = 0.f;
  #pragma unroll
  for (int i = 0; i < 4; i++) {
    qf[i] = bf2f((ushort_t)qv[i]); kf[i] = bf2f((ushort_t)kv[i]);
    sq += qf[i] * qf[i]; sk += kf[i] * kf[i];
  }
  #pragma unroll
  for (int m = 32; m; m >>= 1) { sq += __shfl_down(sq, m); sk += __shfl_down(sk, m); }
  __shared__ float red[8];
  const int wave = tid >> 6, lane = tid & 63;
  if (!lane) { red[wave] = sq; red[4 + wave] = sk; }
  __syncthreads();
  const float rq = rsqrtf((red[0]+red[1]+red[2]+red[3]) * (1.f/1024.f) + 1e-6f)
                   * 0.18033688011112042f;  // fold 0.125*log2(e) into Q
  const float rk = rsqrtf((red[4]+red[5]+red[6]+red[7]) * (1.f/1024.f) + 1e-6f);

  const int h = c >> 6, d = c & 63;
  const float* rp = rope + ((size_t)s * 64 + d) * 2;
  float4 r01 = *(const float4*)(rp);
  float4 r23 = *(const float4*)(rp + 4);
  const float q0 = qf[0]*rq*qw[c], q1 = qf[1]*rq*qw[c+1];
  const float q2 = qf[2]*rq*qw[c+2], q3 = qf[3]*rq*qw[c+3];
  const float k0 = kf[0]*rk*kw[c], k1 = kf[1]*rk*kw[c+1];
  const float k2 = kf[2]*rk*kw[c+2], k3 = kf[3]*rk*kw[c+3];
  s4v qo, ko;
  qo[0] = (short)f2bf(q0 * r01.x - q1 * r01.y);
  qo[1] = (short)f2bf(q1 * r01.z + q0 * r01.w);
  qo[2] = (short)f2bf(q2 * r23.x - q3 * r23.y);
  qo[3] = (short)f2bf(q3 * r23.z + q2 * r23.w);
  ko[0] = (short)f2bf(k0 * r01.x - k1 * r01.y);
  ko[1] = (short)f2bf(k1 * r01.z + k0 * r01.w);
  ko[2] = (short)f2bf(k2 * r23.x - k3 * r23.y);
  ko[3] = (short)f2bf(k3 * r23.z + k2 * r23.w);
  const size_t rowbase = ((size_t)(b * 16 + h) * 2048 + s) * 64;
  const int d_s = (((d >> 3) ^ (s & 7)) << 3) | (d & 7);   // K chunk swizzle
  *(s4v*)(q_r + rowbase + d) = qo;
  *(s4v*)(k_r + rowbase + d_s) = ko;
  *(s4v*)(v_r + rowbase + d) = vv;
}

// ---------------------------------------------------------------------------
// 6) V transpose: [B,H,S,HD] -> [B,H,HD,S], 16B chunks XOR-swizzled within
//    each 64-key group (chunk ^= d&7) for flash's b128 LDS reads.
// ---------------------------------------------------------------------------
__launch_bounds__(256)
__global__ void vtrans(const ushort_t* __restrict__ v_r, ushort_t* __restrict__ v_t)
{
  const int bh = blockIdx.x >> 5, st = blockIdx.x & 31;
  const int s0 = st * 64;
  __shared__ ushort_t tile[64 * 72];
  const int tid = threadIdx.x;
  #pragma unroll
  for (int rep = 0; rep < 2; rep++) {
    const int idx = rep * 256 + tid;
    const int sr = idx >> 3, dc = (idx & 7) << 3;
    s8v val = *(const s8v*)(v_r + ((size_t)bh * 2048 + s0 + sr) * 64 + dc);
    *(s8v*)(tile + sr * 72 + dc) = val;
  }
  __syncthreads();
  #pragma unroll
  for (int rep = 0; rep < 2; rep++) {
    const int idx = rep * 256 + tid;
    const int d = idx >> 3;
    const int scs = (((idx & 7) ^ (d & 7)) << 3);   // swizzled key-chunk
    s8v val;
    const int sc = (idx & 7) << 3;
    #pragma unroll
    for (int j = 0; j < 8; j++) val[j] = (short)tile[(sc + j) * 72 + d];
    *(s8v*)(v_t + ((size_t)bh * 64 + d) * 2048 + s0 + scs) = val;
  }
}

// ---------------------------------------------------------------------------
// 7) Flash attention v2 (unchanged from round 2).
// ---------------------------------------------------------------------------
__launch_bounds__(256)
__global__ void flash(const ushort_t* __restrict__ q_r, const ushort_t* __restrict__ k_r,
                      const ushort_t* __restrict__ v_t, ushort_t* __restrict__ attn)
{
  __shared__ ushort_t Ksh[64 * 64];      // [key][d], chunks ^(key&7)
  __shared__ ushort_t Vsh[64 * 64];      // [d][key], chunks ^(d&7)
  __shared__ ushort_t Psh[4][16 * 64];   // per-wave [q][key], chunks ^(q&7)
  const int bh = blockIdx.x >> 5, qb = blockIdx.x & 31;
  const int tid = threadIdx.x, wave = tid >> 6, lane = tid & 63;
  const int quad = lane >> 4, r = lane & 15;
  const int rx = r & 7;
  const int q0 = qb * 64 + wave * 16;
  const size_t bhS = (size_t)bh * 2048;

  s8v aq0 = *(const s8v*)(q_r + (bhS + q0 + r) * 64 + quad * 8);
  s8v aq1 = *(const s8v*)(q_r + (bhS + q0 + r) * 64 + 32 + quad * 8);

  f4v o[4] = {};
  float mi = -1e30f, li = 0.f;

  const ushort_t* kg = k_r + bhS * 64 + wave * 1024 + lane * 8;
  const ushort_t* vg0 = v_t + ((size_t)bh * 64 + wave * 16 + (lane >> 3)) * 2048
                        + (lane & 7) * 8;
  const ushort_t* vg1 = vg0 + (size_t)8 * 2048;
  ushort_t* kl0 = Ksh + wave * 1024;
  ushort_t* kl1 = Ksh + wave * 1024 + 512;
  ushort_t* vl0 = Vsh + wave * 1024;
  ushort_t* vl1 = Vsh + wave * 1024 + 512;
  ushort_t* pw = &Psh[wave][0];

  for (int kb = 0; kb < 2048; kb += 64) {
    __syncthreads();
    gload16(kg,        kl0);
    gload16(kg + 512,  kl1);
    gload16(vg0 + kb,  vl0);
    gload16(vg1 + kb,  vl1);
    kg += 64 * 64;
    __syncthreads();

    f4v st[4];
    #pragma unroll
    for (int t = 0; t < 4; t++) {
      const ushort_t* krow = Ksh + (t * 16 + r) * 64;
      s8v k0 = *(const s8v*)(krow + (((quad) ^ rx) << 3));
      s8v k1 = *(const s8v*)(krow + (((4 + quad) ^ rx) << 3));
      f4v z = {};
      z = MFMA16(k0, aq0, z);
      z = MFMA16(k1, aq1, z);
      st[t] = z;
    }

    float mloc = st[0][0];
    #pragma unroll
    for (int t = 0; t < 4; t++)
      #pragma unroll
      for (int rr = 0; rr < 4; rr++) mloc = fmaxf(mloc, st[t][rr]);
    mloc = fmaxf(mloc, __shfl_xor(mloc, 16));
    mloc = fmaxf(mloc, __shfl_xor(mloc, 32));
    const float mn = fmaxf(mi, mloc);
    const float al = exp2f(mi - mn);
    float ls = 0.f;
    float p[4][4];
    #pragma unroll
    for (int t = 0; t < 4; t++)
      #pragma unroll
      for (int rr = 0; rr < 4; rr++) {
        p[t][rr] = exp2f(st[t][rr] - mn);
        ls += p[t][rr];
      }
    ls += __shfl_xor(ls, 16);
    ls += __shfl_xor(ls, 32);
    li = al * li + ls;
    mi = mn;

    #pragma unroll
    for (int t = 0; t < 4; t++) {
      s4v pb;
      pb[0] = (short)f2bf(p[t][0]); pb[1] = (short)f2bf(p[t][1]);
      pb[2] = (short)f2bf(p[t][2]); pb[3] = (short)f2bf(p[t][3]);
      const int idx = r * 64 + (((((t << 1) | (quad >> 1))) ^ rx) << 3) + (quad & 1) * 4;
      *(s4v*)(pw + idx) = pb;
    }

    float alo[4];
    #pragma unroll
    for (int rr = 0; rr < 4; rr++) alo[rr] = __shfl(al, quad * 4 + rr);
    #pragma unroll
    for (int nt = 0; nt < 4; nt++)
      #pragma unroll
      for (int rr = 0; rr < 4; rr++) o[nt][rr] *= alo[rr];

    asm volatile("s_waitcnt lgkmcnt(0)" ::: "memory");

    #pragma unroll
    for (int kc = 0; kc < 2; kc++) {
      s8v ap = *(const s8v*)(pw + r * 64 + ((((kc << 2) | quad) ^ rx) << 3));
      #pragma unroll
      for (int nt = 0; nt < 4; nt++) {
        s8v bv = *(const s8v*)(Vsh + (nt * 16 + r) * 64 + ((((kc << 2) | quad) ^ rx) << 3));
        o[nt] = MFMA16(ap, bv, o[nt]);
      }
    }
  }

  const int h = bh & 15, b = bh >> 4;
  const float linv = 1.f / li;
  #pragma unroll
  for (int rr = 0; rr < 4; rr++) {
    const float inv = __shfl(linv, quad * 4 + rr);
    const size_t orow = ((size_t)(b * 2048 + q0 + quad * 4 + rr)) * 1024 + h * 64;
    #pragma unroll
    for (int nt = 0; nt < 4; nt++)
      attn[orow + nt * 16 + r] = f2bf(o[nt][rr] * inv);
  }
}

// ---------------------------------------------------------------------------
// 8) RMSNorm3 + mlp modulation -> nm bf16
// ---------------------------------------------------------------------------
__launch_bounds__(256)
__global__ void rms3_mod(const float* __restrict__ h, const float* __restrict__ emb,
                         const float* __restrict__ w3, ushort_t* __restrict__ nm)
{
  const int row = blockIdx.x, b = row >> 11, tid = threadIdx.x;
  const float* hr = h + (size_t)row * 1024;
  const int c = tid * 4;
  float4 v = *(const float4*)(hr + c);
  float s2 = v.x*v.x + v.y*v.y + v.z*v.z + v.w*v.w;
  #pragma unroll
  for (int m = 32; m; m >>= 1) s2 += __shfl_down(s2, m);
  __shared__ float red[4];
  const int wave = tid >> 6, lane = tid & 63;
  if (!lane) red[wave] = s2;
  __syncthreads();
  const float rms = rsqrtf((red[0] + red[1] + red[2] + red[3]) * (1.f / 1024.f) + 1e-6f);
  const float* sh = emb + b * 6144 + 3072;
  const float* sc = emb + b * 6144 + 4096;
  float4 shv = *(const float4*)(sh + c);
  float4 scv = *(const float4*)(sc + c);
  float4 wv  = *(const float4*)(w3 + c);
  s4v ov;
  ov[0] = (short)f2bf(v.x * rms * wv.x * (1.f + scv.x) + shv.x);
  ov[1] = (short)f2bf(v.y * rms * wv.y * (1.f + scv.y) + shv.y);
  ov[2] = (short)f2bf(v.z * rms * wv.z * (1.f + scv.z) + shv.z);
  ov[3] = (short)f2bf(v.w * rms * wv.w * (1.f + scv.w) + shv.w);
  *(s4v*)(nm + (size_t)row * 1024 + c) = ov;
}

// ---------------------------------------------------------------------------
// host launcher
// ---------------------------------------------------------------------------
extern "C" void kernel_launch(void* const* d_in, const int* in_sizes, int n_in,
                              void* d_out, int out_size, void* d_ws, size_t ws_size,
                              hipStream_t stream)
{
  const float* x    = (const float*)d_in[0];
  const float* ts   = (const float*)d_in[1];
  const float* rope = (const float*)d_in[2];
  const float* adw  = (const float*)d_in[3];
  const float* adb  = (const float*)d_in[4];
  const float* wq   = (const float*)d_in[5];
  const float* wk   = (const float*)d_in[6];
  const float* wv   = (const float*)d_in[7];
  const float* wo   = (const float*)d_in[8];
  const float* qnw  = (const float*)d_in[9];
  const float* knw  = (const float*)d_in[10];
  const float* n3w  = (const float*)d_in[11];
  const float* f1w  = (const float*)d_in[12];
  const float* f1b  = (const float*)d_in[13];
  const float* f2w  = (const float*)d_in[14];
  const float* f2b  = (const float*)d_in[15];

  char* ws = (char*)d_ws;
  ushort_t* WQKV = (ushort_t*)(ws + 0);          //  6 MB
  ushort_t* WO   = (ushort_t*)(ws + 6291456);    //  2 MB
  ushort_t* F1   = (ushort_t*)(ws + 8388608);    //  8 MB
  ushort_t* F2   = (ushort_t*)(ws + 16777216);   //  8 MB
  float*    EMB  = (float*)   (ws + 25165824);   //  48 KB
  float*    H    = (float*)   (ws + 25214976);   // 16 MB
  ushort_t* XM   = (ushort_t*)(ws + 41992192);   //  8 MB  (later: ATTN)
  ushort_t* QKV  = (ushort_t*)(ws + 50380800);   // 24 MB  (later: NM)
  ushort_t* QR   = (ushort_t*)(ws + 75546624);   //  8 MB  (later: FF1 spans 32MB)
  ushort_t* KR   = (ushort_t*)(ws + 83935232);   //  8 MB
  ushort_t* VR   = (ushort_t*)(ws + 92323840);   //  8 MB
  ushort_t* VT   = (ushort_t*)(ws + 100712448);  //  8 MB
  ushort_t* ATTN = XM;
  ushort_t* NM   = QKV;
  ushort_t* FF1  = QR;

  convert_w<<<12288, 256, 0, stream>>>(wq, wk, wv, wo, f1w, f2w, WQKV, WO, F1, F2);
  adaln<<<1536, 256, 0, stream>>>(ts, adw, adb, EMB);
  ln_mod<<<4096, 256, 0, stream>>>(x, EMB, XM);
  gemm_bt<0, 128><<<dim3(24, 32), 256, 0, stream>>>(XM, WQKV, 1024, 3072,
      QKV, nullptr, nullptr, nullptr, nullptr, 0);
  qkv_post<<<4096, 256, 0, stream>>>(QKV, rope, qnw, knw, QR, KR, VR);
  vtrans<<<1024, 256, 0, stream>>>(VR, VT);
  flash<<<1024, 256, 0, stream>>>(QR, KR, VT, ATTN);
  gemm_bt<1, 64><<<dim3(16, 32), 256, 0, stream>>>(ATTN, WO, 1024, 1024,
      nullptr, H, nullptr, x, EMB, 2048);
  rms3_mod<<<4096, 256, 0, stream>>>(H, EMB, n3w, NM);
  gemm_bt<2, 128><<<dim3(32, 32), 256, 0, stream>>>(NM, F1, 1024, 4096,
      FF1, nullptr, f1b, nullptr, nullptr, 0);
  gemm_bt<3, 64><<<dim3(16, 32), 256, 0, stream>>>(FF1, F2, 4096, 1024,
      nullptr, (float*)d_out, f2b, H, EMB, 5120);
}

// Round 4
// 434.434 us; speedup vs baseline: 1.2997x; 1.0171x over previous
//
#include <hip/hip_runtime.h>
#include <cstdint>
#include <cstddef>

typedef unsigned short ushort_t;
typedef __attribute__((ext_vector_type(8))) short s8v;
typedef __attribute__((ext_vector_type(4))) short s4v;
typedef __attribute__((ext_vector_type(4))) float f4v;

#define MFMA16(a, b, c) __builtin_amdgcn_mfma_f32_16x16x32_bf16(a, b, c, 0, 0, 0)

__device__ __forceinline__ ushort_t f2bf(float f) {
  union { float f; unsigned u; } a; a.f = f;
  return (ushort_t)((a.u + 0x7fffu + ((a.u >> 16) & 1u)) >> 16);
}
__device__ __forceinline__ float bf2f(ushort_t h) {
  union { unsigned u; float f; } a; a.u = ((unsigned)h) << 16; return a.f;
}
__device__ __forceinline__ unsigned fbits(float f) {
  union { float f; unsigned u; } a; a.f = f; return a.u;
}

// async global->LDS, 16B per lane; LDS dest is wave-uniform base + lane*16
__device__ __forceinline__ void gload16(const void* g, void* l) {
  __builtin_amdgcn_global_load_lds(
      (__attribute__((address_space(1))) void*)(uintptr_t)g,
      (__attribute__((address_space(3))) void*)(unsigned)(uintptr_t)l,
      16, 0, 0);
}

// ---------------------------------------------------------------------------
// 1) fp32 -> bf16 weight conversion. grid = 12288 blocks x 256 (1024 elem/blk)
// ---------------------------------------------------------------------------
__launch_bounds__(256)
__global__ void convert_w(const float* __restrict__ wq, const float* __restrict__ wk,
                          const float* __restrict__ wv, const float* __restrict__ wo,
                          const float* __restrict__ f1, const float* __restrict__ f2,
                          ushort_t* __restrict__ dqkv, ushort_t* __restrict__ dwo,
                          ushort_t* __restrict__ df1, ushort_t* __restrict__ df2)
{
  const int blk = blockIdx.x;
  const float* src; ushort_t* dst; int off;
  if      (blk < 1024) { src = wq; dst = dqkv;            off = blk; }
  else if (blk < 2048) { src = wk; dst = dqkv + 1048576;  off = blk - 1024; }
  else if (blk < 3072) { src = wv; dst = dqkv + 2097152;  off = blk - 2048; }
  else if (blk < 4096) { src = wo; dst = dwo;             off = blk - 3072; }
  else if (blk < 8192) { src = f1; dst = df1;             off = blk - 4096; }
  else                 { src = f2; dst = df2;             off = blk - 8192; }
  const int idx = off * 1024 + threadIdx.x * 4;
  float4 v = *(const float4*)(src + idx);
  s4v o;
  o[0] = (short)f2bf(v.x); o[1] = (short)f2bf(v.y);
  o[2] = (short)f2bf(v.z); o[3] = (short)f2bf(v.w);
  *(s4v*)(dst + idx) = o;
}

// ---------------------------------------------------------------------------
// 2) adaln: emb[b][j] = sum_d silu(ts[b][d]) * w[j][d] + bias[j]
// ---------------------------------------------------------------------------
__launch_bounds__(256)
__global__ void adaln(const float* __restrict__ ts, const float* __restrict__ w,
                      const float* __restrict__ bias, float* __restrict__ emb)
{
  const int j = blockIdx.x * 4 + (threadIdx.x >> 6);
  const int lane = threadIdx.x & 63;
  const float* wr = w + (size_t)j * 1024;
  float s0 = 0.f, s1 = 0.f;
  for (int i = lane; i < 1024; i += 64) {
    const float wv = wr[i];
    const float t0 = ts[i], t1 = ts[1024 + i];
    s0 += wv * (t0 / (1.f + __expf(-t0)));
    s1 += wv * (t1 / (1.f + __expf(-t1)));
  }
  #pragma unroll
  for (int m = 32; m; m >>= 1) { s0 += __shfl_down(s0, m); s1 += __shfl_down(s1, m); }
  if (!lane) { emb[j] = s0 + bias[j]; emb[6144 + j] = s1 + bias[j]; }
}

// ---------------------------------------------------------------------------
// 3) LayerNorm + msa modulation -> xm bf16. one block per row.
// ---------------------------------------------------------------------------
__launch_bounds__(256)
__global__ void ln_mod(const float* __restrict__ x, const float* __restrict__ emb,
                       ushort_t* __restrict__ xm)
{
  const int row = blockIdx.x, b = row >> 11, tid = threadIdx.x;
  const float* xr = x + (size_t)row * 1024;
  const int c = tid * 4;
  float4 v = *(const float4*)(xr + c);
  float s  = v.x + v.y + v.z + v.w;
  float s2 = v.x*v.x + v.y*v.y + v.z*v.z + v.w*v.w;
  #pragma unroll
  for (int m = 32; m; m >>= 1) { s += __shfl_down(s, m); s2 += __shfl_down(s2, m); }
  __shared__ float red[8];
  const int wave = tid >> 6, lane = tid & 63;
  if (!lane) { red[wave] = s; red[4 + wave] = s2; }
  __syncthreads();
  const float mu = (red[0] + red[1] + red[2] + red[3]) * (1.f / 1024.f);
  const float ms = (red[4] + red[5] + red[6] + red[7]) * (1.f / 1024.f);
  const float rstd = rsqrtf(ms - mu * mu + 1e-6f);
  const float* sh = emb + b * 6144;
  const float* sc = emb + b * 6144 + 1024;
  float4 shv = *(const float4*)(sh + c);
  float4 scv = *(const float4*)(sc + c);
  s4v ov;
  ov[0] = (short)f2bf((v.x - mu) * rstd * (1.f + scv.x) + shv.x);
  ov[1] = (short)f2bf((v.y - mu) * rstd * (1.f + scv.y) + shv.y);
  ov[2] = (short)f2bf((v.z - mu) * rstd * (1.f + scv.z) + shv.z);
  ov[3] = (short)f2bf((v.w - mu) * rstd * (1.f + scv.w) + shv.w);
  *(s4v*)(xm + (size_t)row * 1024 + c) = ov;
}

// ---------------------------------------------------------------------------
// 4) bf16 B^T GEMM, double-buffered LDS (unchanged from round 3).
// ---------------------------------------------------------------------------
template<int EPI, int TN>
__launch_bounds__(256)
__global__ void gemm_bt(const ushort_t* __restrict__ A, const ushort_t* __restrict__ Bw,
                        int K, int N,
                        ushort_t* __restrict__ outb, float* __restrict__ outf,
                        const float* __restrict__ bias, const float* __restrict__ resid,
                        const float* __restrict__ emb, int gate_off)
{
  constexpr int JN = TN / 32;
  constexpr int BUFB = TN * 32;
  __shared__ ushort_t As[2 * 128 * 32];
  __shared__ ushort_t Bs[2 * BUFB];
  const int tid = threadIdx.x;
  const int wave = tid >> 6, lane = tid & 63;
  const int quad = lane >> 4, r = lane & 15;
  const int m0 = blockIdx.y * 128, n0 = blockIdx.x * TN;
  const int wm = (wave >> 1) * 64, wn = (wave & 1) * (TN / 2);

  const int srow = wave * 16 + (lane >> 2);
  const int scol = (lane & 3) * 8;
  const ushort_t* ag = A  + (size_t)(m0 + srow) * K + scol;
  const ushort_t* bg = Bw + (size_t)(n0 + srow) * K + scol;
  const size_t rowK64 = (size_t)64 * K;

  f4v acc[4][JN] = {};

  {
    ushort_t* as = As + wave * 512;
    ushort_t* bs = Bs + wave * 512;
    gload16(ag,          as);
    gload16(ag + rowK64, as + 2048);
    gload16(bg,          bs);
    if (TN == 128) gload16(bg + rowK64, bs + 2048);
    ag += 32; bg += 32;
  }

  const int nIter = K >> 5;
  int cur = 0;
  for (int it = 0; it < nIter - 1; it++) {
    __syncthreads();
    {
      ushort_t* as = As + (cur ^ 1) * 4096 + wave * 512;
      ushort_t* bs = Bs + (cur ^ 1) * BUFB + wave * 512;
      gload16(ag,          as);
      gload16(ag + rowK64, as + 2048);
      gload16(bg,          bs);
      if (TN == 128) gload16(bg + rowK64, bs + 2048);
      ag += 32; bg += 32;
    }
    const ushort_t* ab = As + cur * 4096;
    const ushort_t* bb = Bs + cur * BUFB;
    s8v af[4], bf[JN];
    #pragma unroll
    for (int i = 0; i < 4; i++)
      af[i] = *(const s8v*)(ab + (wm + i * 16 + r) * 32 + quad * 8);
    #pragma unroll
    for (int j = 0; j < JN; j++)
      bf[j] = *(const s8v*)(bb + (wn + j * 16 + r) * 32 + quad * 8);
    #pragma unroll
    for (int i = 0; i < 4; i++)
      #pragma unroll
      for (int j = 0; j < JN; j++)
        acc[i][j] = MFMA16(af[i], bf[j], acc[i][j]);
    cur ^= 1;
  }
  __syncthreads();
  {
    const ushort_t* ab = As + cur * 4096;
    const ushort_t* bb = Bs + cur * BUFB;
    s8v af[4], bf[JN];
    #pragma unroll
    for (int i = 0; i < 4; i++)
      af[i] = *(const s8v*)(ab + (wm + i * 16 + r) * 32 + quad * 8);
    #pragma unroll
    for (int j = 0; j < JN; j++)
      bf[j] = *(const s8v*)(bb + (wn + j * 16 + r) * 32 + quad * 8);
    #pragma unroll
    for (int i = 0; i < 4; i++)
      #pragma unroll
      for (int j = 0; j < JN; j++)
        acc[i][j] = MFMA16(af[i], bf[j], acc[i][j]);
  }

  #pragma unroll
  for (int i = 0; i < 4; i++) {
    const int row = m0 + wm + i * 16 + quad * 4;
    #pragma unroll
    for (int j = 0; j < JN; j++) {
      const int col = n0 + wn + j * 16 + r;
      #pragma unroll
      for (int rr = 0; rr < 4; rr++) {
        float v = acc[i][j][rr];
        const int rw = row + rr;
        const size_t idx = (size_t)rw * N + col;
        if (EPI == 0) {
          outb[idx] = f2bf(v);
        } else if (EPI == 1) {
          const int b = rw >> 11;
          outf[idx] = resid[idx] + emb[b * 6144 + gate_off + col] * v;
        } else if (EPI == 2) {
          v += bias[col];
          const float u = 0.7978845608028654f * (v + 0.044715f * v * v * v);
          const float e = __expf(2.f * u);
          const float th = 1.f - 2.f / (e + 1.f);
          outb[idx] = f2bf(0.5f * v * (1.f + th));
        } else {
          const int b = rw >> 11;
          outf[idx] = resid[idx] + emb[b * 6144 + gate_off + col] * (v + bias[col]);
        }
      }
    }
  }
}

// ---------------------------------------------------------------------------
// 5) QKV post: RMSNorm + RoPE + layout (unchanged from round 3).
// ---------------------------------------------------------------------------
__launch_bounds__(256)
__global__ void qkv_post(const ushort_t* __restrict__ qkv, const float* __restrict__ rope,
                         const float* __restrict__ qw, const float* __restrict__ kw,
                         ushort_t* __restrict__ q_r, ushort_t* __restrict__ k_r,
                         ushort_t* __restrict__ v_r)
{
  const int row = blockIdx.x, b = row >> 11, s = row & 2047, tid = threadIdx.x;
  const ushort_t* base = qkv + (size_t)row * 3072;
  const int c = tid * 4;
  s4v qv = *(const s4v*)(base + c);
  s4v kv = *(const s4v*)(base + 1024 + c);
  s4v vv = *(const s4v*)(base + 2048 + c);
  float qf[4], kf[4]; float sq = 0.f, sk = 0.f;
  #pragma unroll
  for (int i = 0; i < 4; i++) {
    qf[i] = bf2f((ushort_t)qv[i]); kf[i] = bf2f((ushort_t)kv[i]);
    sq += qf[i] * qf[i]; sk += kf[i] * kf[i];
  }
  #pragma unroll
  for (int m = 32; m; m >>= 1) { sq += __shfl_down(sq, m); sk += __shfl_down(sk, m); }
  __shared__ float red[8];
  const int wave = tid >> 6, lane = tid & 63;
  if (!lane) { red[wave] = sq; red[4 + wave] = sk; }
  __syncthreads();
  const float rq = rsqrtf((red[0]+red[1]+red[2]+red[3]) * (1.f/1024.f) + 1e-6f)
                   * 0.18033688011112042f;  // fold 0.125*log2(e) into Q
  const float rk = rsqrtf((red[4]+red[5]+red[6]+red[7]) * (1.f/1024.f) + 1e-6f);

  const int h = c >> 6, d = c & 63;
  const float* rp = rope + ((size_t)s * 64 + d) * 2;
  float4 r01 = *(const float4*)(rp);
  float4 r23 = *(const float4*)(rp + 4);
  const float q0 = qf[0]*rq*qw[c], q1 = qf[1]*rq*qw[c+1];
  const float q2 = qf[2]*rq*qw[c+2], q3 = qf[3]*rq*qw[c+3];
  const float k0 = kf[0]*rk*kw[c], k1 = kf[1]*rk*kw[c+1];
  const float k2 = kf[2]*rk*kw[c+2], k3 = kf[3]*rk*kw[c+3];
  s4v qo, ko;
  qo[0] = (short)f2bf(q0 * r01.x - q1 * r01.y);
  qo[1] = (short)f2bf(q1 * r01.z + q0 * r01.w);
  qo[2] = (short)f2bf(q2 * r23.x - q3 * r23.y);
  qo[3] = (short)f2bf(q3 * r23.z + q2 * r23.w);
  ko[0] = (short)f2bf(k0 * r01.x - k1 * r01.y);
  ko[1] = (short)f2bf(k1 * r01.z + k0 * r01.w);
  ko[2] = (short)f2bf(k2 * r23.x - k3 * r23.y);
  ko[3] = (short)f2bf(k3 * r23.z + k2 * r23.w);
  const size_t rowbase = ((size_t)(b * 16 + h) * 2048 + s) * 64;
  const int d_s = (((d >> 3) ^ (s & 7)) << 3) | (d & 7);   // K chunk swizzle
  *(s4v*)(q_r + rowbase + d) = qo;
  *(s4v*)(k_r + rowbase + d_s) = ko;
  *(s4v*)(v_r + rowbase + d) = vv;
}

// ---------------------------------------------------------------------------
// 6) V transpose (unchanged from round 3).
// ---------------------------------------------------------------------------
__launch_bounds__(256)
__global__ void vtrans(const ushort_t* __restrict__ v_r, ushort_t* __restrict__ v_t)
{
  const int bh = blockIdx.x >> 5, st = blockIdx.x & 31;
  const int s0 = st * 64;
  __shared__ ushort_t tile[64 * 72];
  const int tid = threadIdx.x;
  #pragma unroll
  for (int rep = 0; rep < 2; rep++) {
    const int idx = rep * 256 + tid;
    const int sr = idx >> 3, dc = (idx & 7) << 3;
    s8v val = *(const s8v*)(v_r + ((size_t)bh * 2048 + s0 + sr) * 64 + dc);
    *(s8v*)(tile + sr * 72 + dc) = val;
  }
  __syncthreads();
  #pragma unroll
  for (int rep = 0; rep < 2; rep++) {
    const int idx = rep * 256 + tid;
    const int d = idx >> 3;
    const int scs = (((idx & 7) ^ (d & 7)) << 3);
    s8v val;
    const int sc = (idx & 7) << 3;
    #pragma unroll
    for (int j = 0; j < 8; j++) val[j] = (short)tile[(sc + j) * 72 + d];
    *(s8v*)(v_t + ((size_t)bh * 64 + d) * 2048 + s0 + scs) = val;
  }
}

// ---------------------------------------------------------------------------
// 7) Flash attention v3. 128-key tiles (16 iters). S^T = K*Q^T; softmax
//    in-lane over 32 scores + 2 bpermute; raw v_exp_f32; P packed to bf16
//    via v_perm_b32 (2 floats -> 1 dword) and written as b64; PV from
//    swizzled Psh/Vsh. LDS 48 KB.
// ---------------------------------------------------------------------------
__launch_bounds__(256)
__global__ void flash(const ushort_t* __restrict__ q_r, const ushort_t* __restrict__ k_r,
                      const ushort_t* __restrict__ v_t, ushort_t* __restrict__ attn)
{
  __shared__ ushort_t Ksh[128 * 64];     // [key][d], 8 chunks ^(key&7)
  __shared__ ushort_t Vsh[64 * 128];     // [d][key], 16 chunks (c&8)|((c&7)^(d&7))
  __shared__ ushort_t Psh[4][16 * 128];  // per-wave [q][key], same 16-chunk swizzle
  const int bh = blockIdx.x >> 5, qb = blockIdx.x & 31;
  const int tid = threadIdx.x, wave = tid >> 6, lane = tid & 63;
  const int quad = lane >> 4, r = lane & 15;
  const int rx = r & 7;
  const int q0 = qb * 64 + wave * 16;
  const size_t bhS = (size_t)bh * 2048;

  s8v aq0 = *(const s8v*)(q_r + (bhS + q0 + r) * 64 + quad * 8);
  s8v aq1 = *(const s8v*)(q_r + (bhS + q0 + r) * 64 + 32 + quad * 8);

  f4v o[4] = {};
  float mi = -1e30f, li = 0.f;

  // K staging: wave covers key rows wave*32..+31 (4 calls x 8 rows x 64 d)
  const ushort_t* kg = k_r + (bhS + wave * 32 + (lane >> 3)) * 64 + (lane & 7) * 8;
  ushort_t* kl = Ksh + wave * 2048 + lane * 8;
  // V staging: wave covers d rows wave*16..+15 (4 calls x 4 rows x 128 keys)
  const ushort_t* vg = v_t + ((size_t)bh * 64 + wave * 16 + (lane >> 4)) * 2048
                       + (lane & 15) * 8;
  ushort_t* vl = Vsh + (wave * 16 + (lane >> 4)) * 128 + (lane & 15) * 8;
  ushort_t* pw = &Psh[wave][0];

  for (int kb = 0; kb < 2048; kb += 128) {
    __syncthreads();
    #pragma unroll
    for (int c = 0; c < 4; c++) {
      gload16(kg + (size_t)(kb + c * 8) * 64, kl + c * 512);
      gload16(vg + kb + (size_t)(c * 4) * 2048, vl + c * 512);
    }
    __syncthreads();

    // S^T[key][q]: 8 row-tiles of 16 keys
    f4v st[8];
    #pragma unroll
    for (int t = 0; t < 8; t++) {
      const ushort_t* krow = Ksh + (t * 16 + r) * 64;
      s8v k0 = *(const s8v*)(krow + ((quad ^ rx) << 3));
      s8v k1 = *(const s8v*)(krow + (((4 + quad) ^ rx) << 3));
      f4v z = {};
      z = MFMA16(k0, aq0, z);
      z = MFMA16(k1, aq1, z);
      st[t] = z;
    }

    // online softmax for q=r: 32 in-lane scores, 2 cross-lane hops
    float mloc = st[0][0];
    #pragma unroll
    for (int t = 0; t < 8; t++)
      #pragma unroll
      for (int rr = 0; rr < 4; rr++) mloc = fmaxf(mloc, st[t][rr]);
    mloc = fmaxf(mloc, __shfl_xor(mloc, 16));
    mloc = fmaxf(mloc, __shfl_xor(mloc, 32));
    const float mn = fmaxf(mi, mloc);
    const float al = __builtin_amdgcn_exp2f(mi - mn);
    float p[8][4];
    float ls = 0.f;
    #pragma unroll
    for (int t = 0; t < 8; t++)
      #pragma unroll
      for (int rr = 0; rr < 4; rr++) {
        p[t][rr] = __builtin_amdgcn_exp2f(st[t][rr] - mn);
        ls += p[t][rr];
      }
    ls += __shfl_xor(ls, 16);
    ls += __shfl_xor(ls, 32);
    li = al * li + ls;
    mi = mn;

    // pack P -> bf16 pairs via v_perm, write b64 (4 keys/lane/tile-row)
    #pragma unroll
    for (int t = 0; t < 8; t++) {
      const unsigned u0 = fbits(p[t][0]) + 0x8000u;
      const unsigned u1 = fbits(p[t][1]) + 0x8000u;
      const unsigned u2 = fbits(p[t][2]) + 0x8000u;
      const unsigned u3 = fbits(p[t][3]) + 0x8000u;
      uint2 pk;
      pk.x = __builtin_amdgcn_perm(u1, u0, 0x07060302u);
      pk.y = __builtin_amdgcn_perm(u3, u2, 0x07060302u);
      const int cw = t * 2 + (quad >> 1);
      const int sc = (cw & 8) | ((cw & 7) ^ rx);
      *(uint2*)(pw + r * 128 + (sc << 3) + (quad & 1) * 4) = pk;
    }

    // rescale O rows (alpha for q = quad*4+rr lives in lane quad*4+rr)
    float alo[4];
    #pragma unroll
    for (int rr = 0; rr < 4; rr++) alo[rr] = __shfl(al, quad * 4 + rr);
    #pragma unroll
    for (int nt = 0; nt < 4; nt++)
      #pragma unroll
      for (int rr = 0; rr < 4; rr++) o[nt][rr] *= alo[rr];

    asm volatile("s_waitcnt lgkmcnt(0)" ::: "memory");  // P write -> read, same wave

    // O += P * V  (K = 32 keys per MFMA, 4 chunks of the 128-key tile)
    #pragma unroll
    for (int kc = 0; kc < 4; kc++) {
      const int c = kc * 4 + quad;
      const int sc = (c & 8) | ((c & 7) ^ rx);
      s8v ap = *(const s8v*)(pw + r * 128 + (sc << 3));
      #pragma unroll
      for (int nt = 0; nt < 4; nt++) {
        s8v bv = *(const s8v*)(Vsh + (nt * 16 + r) * 128 + (sc << 3));
        o[nt] = MFMA16(ap, bv, o[nt]);
      }
    }
  }

  const int h = bh & 15, b = bh >> 4;
  const float linv = 1.f / li;
  #pragma unroll
  for (int rr = 0; rr < 4; rr++) {
    const float inv = __shfl(linv, quad * 4 + rr);
    const size_t orow = ((size_t)(b * 2048 + q0 + quad * 4 + rr)) * 1024 + h * 64;
    #pragma unroll
    for (int nt = 0; nt < 4; nt++)
      attn[orow + nt * 16 + r] = f2bf(o[nt][rr] * inv);
  }
}

// ---------------------------------------------------------------------------
// 8) RMSNorm3 + mlp modulation -> nm bf16
// ---------------------------------------------------------------------------
__launch_bounds__(256)
__global__ void rms3_mod(const float* __restrict__ h, const float* __restrict__ emb,
                         const float* __restrict__ w3, ushort_t* __restrict__ nm)
{
  const int row = blockIdx.x, b = row >> 11, tid = threadIdx.x;
  const float* hr = h + (size_t)row * 1024;
  const int c = tid * 4;
  float4 v = *(const float4*)(hr + c);
  float s2 = v.x*v.x + v.y*v.y + v.z*v.z + v.w*v.w;
  #pragma unroll
  for (int m = 32; m; m >>= 1) s2 += __shfl_down(s2, m);
  __shared__ float red[4];
  const int wave = tid >> 6, lane = tid & 63;
  if (!lane) red[wave] = s2;
  __syncthreads();
  const float rms = rsqrtf((red[0] + red[1] + red[2] + red[3]) * (1.f / 1024.f) + 1e-6f);
  const float* sh = emb + b * 6144 + 3072;
  const float* sc = emb + b * 6144 + 4096;
  float4 shv = *(const float4*)(sh + c);
  float4 scv = *(const float4*)(sc + c);
  float4 wv  = *(const float4*)(w3 + c);
  s4v ov;
  ov[0] = (short)f2bf(v.x * rms * wv.x * (1.f + scv.x) + shv.x);
  ov[1] = (short)f2bf(v.y * rms * wv.y * (1.f + scv.y) + shv.y);
  ov[2] = (short)f2bf(v.z * rms * wv.z * (1.f + scv.z) + shv.z);
  ov[3] = (short)f2bf(v.w * rms * wv.w * (1.f + scv.w) + shv.w);
  *(s4v*)(nm + (size_t)row * 1024 + c) = ov;
}

// ---------------------------------------------------------------------------
// host launcher
// ---------------------------------------------------------------------------
extern "C" void kernel_launch(void* const* d_in, const int* in_sizes, int n_in,
                              void* d_out, int out_size, void* d_ws, size_t ws_size,
                              hipStream_t stream)
{
  const float* x    = (const float*)d_in[0];
  const float* ts   = (const float*)d_in[1];
  const float* rope = (const float*)d_in[2];
  const float* adw  = (const float*)d_in[3];
  const float* adb  = (const float*)d_in[4];
  const float* wq   = (const float*)d_in[5];
  const float* wk   = (const float*)d_in[6];
  const float* wv   = (const float*)d_in[7];
  const float* wo   = (const float*)d_in[8];
  const float* qnw  = (const float*)d_in[9];
  const float* knw  = (const float*)d_in[10];
  const float* n3w  = (const float*)d_in[11];
  const float* f1w  = (const float*)d_in[12];
  const float* f1b  = (const float*)d_in[13];
  const float* f2w  = (const float*)d_in[14];
  const float* f2b  = (const float*)d_in[15];

  char* ws = (char*)d_ws;
  ushort_t* WQKV = (ushort_t*)(ws + 0);          //  6 MB
  ushort_t* WO   = (ushort_t*)(ws + 6291456);    //  2 MB
  ushort_t* F1   = (ushort_t*)(ws + 8388608);    //  8 MB
  ushort_t* F2   = (ushort_t*)(ws + 16777216);   //  8 MB
  float*    EMB  = (float*)   (ws + 25165824);   //  48 KB
  float*    H    = (float*)   (ws + 25214976);   // 16 MB
  ushort_t* XM   = (ushort_t*)(ws + 41992192);   //  8 MB  (later: ATTN)
  ushort_t* QKV  = (ushort_t*)(ws + 50380800);   // 24 MB  (later: NM)
  ushort_t* QR   = (ushort_t*)(ws + 75546624);   //  8 MB  (later: FF1 spans 32MB)
  ushort_t* KR   = (ushort_t*)(ws + 83935232);   //  8 MB
  ushort_t* VR   = (ushort_t*)(ws + 92323840);   //  8 MB
  ushort_t* VT   = (ushort_t*)(ws + 100712448);  //  8 MB
  ushort_t* ATTN = XM;
  ushort_t* NM   = QKV;
  ushort_t* FF1  = QR;

  convert_w<<<12288, 256, 0, stream>>>(wq, wk, wv, wo, f1w, f2w, WQKV, WO, F1, F2);
  adaln<<<1536, 256, 0, stream>>>(ts, adw, adb, EMB);
  ln_mod<<<4096, 256, 0, stream>>>(x, EMB, XM);
  gemm_bt<0, 128><<<dim3(24, 32), 256, 0, stream>>>(XM, WQKV, 1024, 3072,
      QKV, nullptr, nullptr, nullptr, nullptr, 0);
  qkv_post<<<4096, 256, 0, stream>>>(QKV, rope, qnw, knw, QR, KR, VR);
  vtrans<<<1024, 256, 0, stream>>>(VR, VT);
  flash<<<1024, 256, 0, stream>>>(QR, KR, VT, ATTN);
  gemm_bt<1, 64><<<dim3(16, 32), 256, 0, stream>>>(ATTN, WO, 1024, 1024,
      nullptr, H, nullptr, x, EMB, 2048);
  rms3_mod<<<4096, 256, 0, stream>>>(H, EMB, n3w, NM);
  gemm_bt<2, 128><<<dim3(32, 32), 256, 0, stream>>>(NM, F1, 1024, 4096,
      FF1, nullptr, f1b, nullptr, nullptr, 0);
  gemm_bt<3, 64><<<dim3(16, 32), 256, 0, stream>>>(FF1, F2, 4096, 1024,
      nullptr, (float*)d_out, f2b, H, EMB, 5120);
}

// Round 5
// 428.031 us; speedup vs baseline: 1.3191x; 1.0150x over previous
//
#include <hip/hip_runtime.h>
#include <cstdint>
#include <cstddef>

typedef unsigned short ushort_t;
typedef __attribute__((ext_vector_type(8))) short s8v;
typedef __attribute__((ext_vector_type(4))) short s4v;
typedef __attribute__((ext_vector_type(4))) float f4v;

#define MFMA16(a, b, c) __builtin_amdgcn_mfma_f32_16x16x32_bf16(a, b, c, 0, 0, 0)

__device__ __forceinline__ ushort_t f2bf(float f) {
  union { float f; unsigned u; } a; a.f = f;
  return (ushort_t)((a.u + 0x7fffu + ((a.u >> 16) & 1u)) >> 16);
}
__device__ __forceinline__ float bf2f(ushort_t h) {
  union { unsigned u; float f; } a; a.u = ((unsigned)h) << 16; return a.f;
}
__device__ __forceinline__ unsigned fbits(float f) {
  union { float f; unsigned u; } a; a.f = f; return a.u;
}

// async global->LDS, 16B per lane; LDS dest is wave-uniform base + lane*16
__device__ __forceinline__ void gload16(const void* g, void* l) {
  __builtin_amdgcn_global_load_lds(
      (__attribute__((address_space(1))) void*)(uintptr_t)g,
      (__attribute__((address_space(3))) void*)(unsigned)(uintptr_t)l,
      16, 0, 0);
}

// ---------------------------------------------------------------------------
// 1) fp32 -> bf16 weight conversion. grid = 12288 blocks x 256 (1024 elem/blk)
// ---------------------------------------------------------------------------
__launch_bounds__(256)
__global__ void convert_w(const float* __restrict__ wq, const float* __restrict__ wk,
                          const float* __restrict__ wv, const float* __restrict__ wo,
                          const float* __restrict__ f1, const float* __restrict__ f2,
                          ushort_t* __restrict__ dqkv, ushort_t* __restrict__ dwo,
                          ushort_t* __restrict__ df1, ushort_t* __restrict__ df2)
{
  const int blk = blockIdx.x;
  const float* src; ushort_t* dst; int off;
  if      (blk < 1024) { src = wq; dst = dqkv;            off = blk; }
  else if (blk < 2048) { src = wk; dst = dqkv + 1048576;  off = blk - 1024; }
  else if (blk < 3072) { src = wv; dst = dqkv + 2097152;  off = blk - 2048; }
  else if (blk < 4096) { src = wo; dst = dwo;             off = blk - 3072; }
  else if (blk < 8192) { src = f1; dst = df1;             off = blk - 4096; }
  else                 { src = f2; dst = df2;             off = blk - 8192; }
  const int idx = off * 1024 + threadIdx.x * 4;
  float4 v = *(const float4*)(src + idx);
  s4v o;
  o[0] = (short)f2bf(v.x); o[1] = (short)f2bf(v.y);
  o[2] = (short)f2bf(v.z); o[3] = (short)f2bf(v.w);
  *(s4v*)(dst + idx) = o;
}

// ---------------------------------------------------------------------------
// 2) adaln: emb[b][j] = sum_d silu(ts[b][d]) * w[j][d] + bias[j]
// ---------------------------------------------------------------------------
__launch_bounds__(256)
__global__ void adaln(const float* __restrict__ ts, const float* __restrict__ w,
                      const float* __restrict__ bias, float* __restrict__ emb)
{
  const int j = blockIdx.x * 4 + (threadIdx.x >> 6);
  const int lane = threadIdx.x & 63;
  const float* wr = w + (size_t)j * 1024;
  float s0 = 0.f, s1 = 0.f;
  for (int i = lane; i < 1024; i += 64) {
    const float wv = wr[i];
    const float t0 = ts[i], t1 = ts[1024 + i];
    const float e0 = __builtin_amdgcn_exp2f(-1.4426950409f * t0);
    const float e1 = __builtin_amdgcn_exp2f(-1.4426950409f * t1);
    s0 += wv * t0 * __builtin_amdgcn_rcpf(1.f + e0);
    s1 += wv * t1 * __builtin_amdgcn_rcpf(1.f + e1);
  }
  #pragma unroll
  for (int m = 32; m; m >>= 1) { s0 += __shfl_down(s0, m); s1 += __shfl_down(s1, m); }
  if (!lane) { emb[j] = s0 + bias[j]; emb[6144 + j] = s1 + bias[j]; }
}

// ---------------------------------------------------------------------------
// 3) LayerNorm + msa modulation -> xm bf16. one block per row.
// ---------------------------------------------------------------------------
__launch_bounds__(256)
__global__ void ln_mod(const float* __restrict__ x, const float* __restrict__ emb,
                       ushort_t* __restrict__ xm)
{
  const int row = blockIdx.x, b = row >> 11, tid = threadIdx.x;
  const float* xr = x + (size_t)row * 1024;
  const int c = tid * 4;
  float4 v = *(const float4*)(xr + c);
  float s  = v.x + v.y + v.z + v.w;
  float s2 = v.x*v.x + v.y*v.y + v.z*v.z + v.w*v.w;
  #pragma unroll
  for (int m = 32; m; m >>= 1) { s += __shfl_down(s, m); s2 += __shfl_down(s2, m); }
  __shared__ float red[8];
  const int wave = tid >> 6, lane = tid & 63;
  if (!lane) { red[wave] = s; red[4 + wave] = s2; }
  __syncthreads();
  const float mu = (red[0] + red[1] + red[2] + red[3]) * (1.f / 1024.f);
  const float ms = (red[4] + red[5] + red[6] + red[7]) * (1.f / 1024.f);
  const float rstd = rsqrtf(ms - mu * mu + 1e-6f);
  const float* sh = emb + b * 6144;
  const float* sc = emb + b * 6144 + 1024;
  float4 shv = *(const float4*)(sh + c);
  float4 scv = *(const float4*)(sc + c);
  s4v ov;
  ov[0] = (short)f2bf((v.x - mu) * rstd * (1.f + scv.x) + shv.x);
  ov[1] = (short)f2bf((v.y - mu) * rstd * (1.f + scv.y) + shv.y);
  ov[2] = (short)f2bf((v.z - mu) * rstd * (1.f + scv.z) + shv.z);
  ov[3] = (short)f2bf((v.w - mu) * rstd * (1.f + scv.w) + shv.w);
  *(s4v*)(xm + (size_t)row * 1024 + c) = ov;
}

// ---------------------------------------------------------------------------
// 4) bf16 B^T GEMM. K-loop unrolled x2 with STATIC double buffers (compile-
//    time LDS addresses -> loop-invariant hoisting), 1 barrier per tile.
//    Tile 128 x TN, BK=32. Fast-gelu epilogue (exp2+rcp), hoisted bias/gate.
//    EPI: 0 = bf16 store, 1 = h = x + g_msa*o (fp32), 2 = bias+gelu (bf16),
//         3 = out = h + g_mlp*(v+bias) (fp32)
// ---------------------------------------------------------------------------
template<int EPI, int TN>
__launch_bounds__(256)
__global__ void gemm_bt(const ushort_t* __restrict__ A, const ushort_t* __restrict__ Bw,
                        int K, int N,
                        ushort_t* __restrict__ outb, float* __restrict__ outf,
                        const float* __restrict__ bias, const float* __restrict__ resid,
                        const float* __restrict__ emb, int gate_off)
{
  constexpr int JN = TN / 32;
  constexpr int BUFB = TN * 32;
  __shared__ ushort_t As0[128 * 32], As1[128 * 32];
  __shared__ ushort_t Bs0[BUFB],    Bs1[BUFB];
  const int tid = threadIdx.x;
  const int wave = tid >> 6, lane = tid & 63;
  const int quad = lane >> 4, r = lane & 15;
  const int m0 = blockIdx.y * 128, n0 = blockIdx.x * TN;
  const int wm = (wave >> 1) * 64, wn = (wave & 1) * (TN / 2);

  const int srow = wave * 16 + (lane >> 2);
  const int scol = (lane & 3) * 8;
  const ushort_t* ag = A  + (size_t)(m0 + srow) * K + scol;
  const ushort_t* bg = Bw + (size_t)(n0 + srow) * K + scol;
  const size_t rowK64 = (size_t)64 * K;

  f4v acc[4][JN] = {};

  auto stage = [&](ushort_t* as, ushort_t* bs) {
    gload16(ag,          as + wave * 512);
    gload16(ag + rowK64, as + wave * 512 + 2048);
    gload16(bg,          bs + wave * 512);
    if (TN == 128) gload16(bg + rowK64, bs + wave * 512 + 2048);
    ag += 32; bg += 32;
  };
  auto compute = [&](const ushort_t* ab, const ushort_t* bb) {
    s8v af[4], bf[JN];
    #pragma unroll
    for (int i = 0; i < 4; i++)
      af[i] = *(const s8v*)(ab + (wm + i * 16 + r) * 32 + quad * 8);
    #pragma unroll
    for (int j = 0; j < JN; j++)
      bf[j] = *(const s8v*)(bb + (wn + j * 16 + r) * 32 + quad * 8);
    #pragma unroll
    for (int i = 0; i < 4; i++)
      #pragma unroll
      for (int j = 0; j < JN; j++)
        acc[i][j] = MFMA16(af[i], bf[j], acc[i][j]);
  };

  stage(As0, Bs0);
  __syncthreads();                       // tile 0 landed
  const int R = (K >> 6) - 1;            // (K/32)/2 - 1 rounds
  for (int it = 0; it < R; it++) {
    stage(As1, Bs1);                     // prefetch odd tile
    compute(As0, Bs0);
    __syncthreads();                     // odd tile landed; even buffer free
    stage(As0, Bs0);                     // prefetch next even tile
    compute(As1, Bs1);
    __syncthreads();                     // even tile landed; odd buffer free
  }
  stage(As1, Bs1);                       // last odd tile
  compute(As0, Bs0);
  __syncthreads();
  compute(As1, Bs1);

  // ---- epilogue ----
  const int bblk = m0 >> 11;             // batch is uniform per block
  #pragma unroll
  for (int j = 0; j < JN; j++) {
    const int col = n0 + wn + j * 16 + r;
    float bj = 0.f, gj = 0.f;
    if (EPI == 2 || EPI == 3) bj = bias[col];
    if (EPI == 1 || EPI == 3) gj = emb[bblk * 6144 + gate_off + col];
    #pragma unroll
    for (int i = 0; i < 4; i++) {
      const int row = m0 + wm + i * 16 + quad * 4;
      #pragma unroll
      for (int rr = 0; rr < 4; rr++) {
        float v = acc[i][j][rr];
        const size_t idx = (size_t)(row + rr) * N + col;
        if (EPI == 0) {
          outb[idx] = f2bf(v);
        } else if (EPI == 1) {
          outf[idx] = resid[idx] + gj * v;
        } else if (EPI == 2) {
          v += bj;
          // gelu(v) = v * sigmoid(1.5957691*(v + 0.044715 v^3)), exp2 form
          const float t = fmaf(v * v, 0.1029436f, 2.3022083f);
          const float e = __builtin_amdgcn_exp2f(-v * t);
          outb[idx] = f2bf(v * __builtin_amdgcn_rcpf(1.f + e));
        } else {
          outf[idx] = resid[idx] + gj * (v + bj);
        }
      }
    }
  }
}

// ---------------------------------------------------------------------------
// 5) QKV post: RMSNorm + RoPE + layout (unchanged).
// ---------------------------------------------------------------------------
__launch_bounds__(256)
__global__ void qkv_post(const ushort_t* __restrict__ qkv, const float* __restrict__ rope,
                         const float* __restrict__ qw, const float* __restrict__ kw,
                         ushort_t* __restrict__ q_r, ushort_t* __restrict__ k_r,
                         ushort_t* __restrict__ v_r)
{
  const int row = blockIdx.x, b = row >> 11, s = row & 2047, tid = threadIdx.x;
  const ushort_t* base = qkv + (size_t)row * 3072;
  const int c = tid * 4;
  s4v qv = *(const s4v*)(base + c);
  s4v kv = *(const s4v*)(base + 1024 + c);
  s4v vv = *(const s4v*)(base + 2048 + c);
  float qf[4], kf[4]; float sq = 0.f, sk = 0.f;
  #pragma unroll
  for (int i = 0; i < 4; i++) {
    qf[i] = bf2f((ushort_t)qv[i]); kf[i] = bf2f((ushort_t)kv[i]);
    sq += qf[i] * qf[i]; sk += kf[i] * kf[i];
  }
  #pragma unroll
  for (int m = 32; m; m >>= 1) { sq += __shfl_down(sq, m); sk += __shfl_down(sk, m); }
  __shared__ float red[8];
  const int wave = tid >> 6, lane = tid & 63;
  if (!lane) { red[wave] = sq; red[4 + wave] = sk; }
  __syncthreads();
  const float rq = rsqrtf((red[0]+red[1]+red[2]+red[3]) * (1.f/1024.f) + 1e-6f)
                   * 0.18033688011112042f;  // fold 0.125*log2(e) into Q
  const float rk = rsqrtf((red[4]+red[5]+red[6]+red[7]) * (1.f/1024.f) + 1e-6f);

  const int h = c >> 6, d = c & 63;
  const float* rp = rope + ((size_t)s * 64 + d) * 2;
  float4 r01 = *(const float4*)(rp);
  float4 r23 = *(const float4*)(rp + 4);
  const float q0 = qf[0]*rq*qw[c], q1 = qf[1]*rq*qw[c+1];
  const float q2 = qf[2]*rq*qw[c+2], q3 = qf[3]*rq*qw[c+3];
  const float k0 = kf[0]*rk*kw[c], k1 = kf[1]*rk*kw[c+1];
  const float k2 = kf[2]*rk*kw[c+2], k3 = kf[3]*rk*kw[c+3];
  s4v qo, ko;
  qo[0] = (short)f2bf(q0 * r01.x - q1 * r01.y);
  qo[1] = (short)f2bf(q1 * r01.z + q0 * r01.w);
  qo[2] = (short)f2bf(q2 * r23.x - q3 * r23.y);
  qo[3] = (short)f2bf(q3 * r23.z + q2 * r23.w);
  ko[0] = (short)f2bf(k0 * r01.x - k1 * r01.y);
  ko[1] = (short)f2bf(k1 * r01.z + k0 * r01.w);
  ko[2] = (short)f2bf(k2 * r23.x - k3 * r23.y);
  ko[3] = (short)f2bf(k3 * r23.z + k2 * r23.w);
  const size_t rowbase = ((size_t)(b * 16 + h) * 2048 + s) * 64;
  const int d_s = (((d >> 3) ^ (s & 7)) << 3) | (d & 7);   // K chunk swizzle
  *(s4v*)(q_r + rowbase + d) = qo;
  *(s4v*)(k_r + rowbase + d_s) = ko;
  *(s4v*)(v_r + rowbase + d) = vv;
}

// ---------------------------------------------------------------------------
// 6) V transpose (unchanged).
// ---------------------------------------------------------------------------
__launch_bounds__(256)
__global__ void vtrans(const ushort_t* __restrict__ v_r, ushort_t* __restrict__ v_t)
{
  const int bh = blockIdx.x >> 5, st = blockIdx.x & 31;
  const int s0 = st * 64;
  __shared__ ushort_t tile[64 * 72];
  const int tid = threadIdx.x;
  #pragma unroll
  for (int rep = 0; rep < 2; rep++) {
    const int idx = rep * 256 + tid;
    const int sr = idx >> 3, dc = (idx & 7) << 3;
    s8v val = *(const s8v*)(v_r + ((size_t)bh * 2048 + s0 + sr) * 64 + dc);
    *(s8v*)(tile + sr * 72 + dc) = val;
  }
  __syncthreads();
  #pragma unroll
  for (int rep = 0; rep < 2; rep++) {
    const int idx = rep * 256 + tid;
    const int d = idx >> 3;
    const int scs = (((idx & 7) ^ (d & 7)) << 3);
    s8v val;
    const int sc = (idx & 7) << 3;
    #pragma unroll
    for (int j = 0; j < 8; j++) val[j] = (short)tile[(sc + j) * 72 + d];
    *(s8v*)(v_t + ((size_t)bh * 64 + d) * 2048 + s0 + scs) = val;
  }
}

// ---------------------------------------------------------------------------
// 7) Flash attention v3 (unchanged from round 4).
// ---------------------------------------------------------------------------
__launch_bounds__(256)
__global__ void flash(const ushort_t* __restrict__ q_r, const ushort_t* __restrict__ k_r,
                      const ushort_t* __restrict__ v_t, ushort_t* __restrict__ attn)
{
  __shared__ ushort_t Ksh[128 * 64];     // [key][d], 8 chunks ^(key&7)
  __shared__ ushort_t Vsh[64 * 128];     // [d][key], 16 chunks (c&8)|((c&7)^(d&7))
  __shared__ ushort_t Psh[4][16 * 128];  // per-wave [q][key], same 16-chunk swizzle
  const int bh = blockIdx.x >> 5, qb = blockIdx.x & 31;
  const int tid = threadIdx.x, wave = tid >> 6, lane = tid & 63;
  const int quad = lane >> 4, r = lane & 15;
  const int rx = r & 7;
  const int q0 = qb * 64 + wave * 16;
  const size_t bhS = (size_t)bh * 2048;

  s8v aq0 = *(const s8v*)(q_r + (bhS + q0 + r) * 64 + quad * 8);
  s8v aq1 = *(const s8v*)(q_r + (bhS + q0 + r) * 64 + 32 + quad * 8);

  f4v o[4] = {};
  float mi = -1e30f, li = 0.f;

  const ushort_t* kg = k_r + (bhS + wave * 32 + (lane >> 3)) * 64 + (lane & 7) * 8;
  ushort_t* kl = Ksh + wave * 2048 + lane * 8;
  const ushort_t* vg = v_t + ((size_t)bh * 64 + wave * 16 + (lane >> 4)) * 2048
                       + (lane & 15) * 8;
  ushort_t* vl = Vsh + (wave * 16 + (lane >> 4)) * 128 + (lane & 15) * 8;
  ushort_t* pw = &Psh[wave][0];

  for (int kb = 0; kb < 2048; kb += 128) {
    __syncthreads();
    #pragma unroll
    for (int c = 0; c < 4; c++) {
      gload16(kg + (size_t)(kb + c * 8) * 64, kl + c * 512);
      gload16(vg + kb + (size_t)(c * 4) * 2048, vl + c * 512);
    }
    __syncthreads();

    f4v st[8];
    #pragma unroll
    for (int t = 0; t < 8; t++) {
      const ushort_t* krow = Ksh + (t * 16 + r) * 64;
      s8v k0 = *(const s8v*)(krow + ((quad ^ rx) << 3));
      s8v k1 = *(const s8v*)(krow + (((4 + quad) ^ rx) << 3));
      f4v z = {};
      z = MFMA16(k0, aq0, z);
      z = MFMA16(k1, aq1, z);
      st[t] = z;
    }

    float mloc = st[0][0];
    #pragma unroll
    for (int t = 0; t < 8; t++)
      #pragma unroll
      for (int rr = 0; rr < 4; rr++) mloc = fmaxf(mloc, st[t][rr]);
    mloc = fmaxf(mloc, __shfl_xor(mloc, 16));
    mloc = fmaxf(mloc, __shfl_xor(mloc, 32));
    const float mn = fmaxf(mi, mloc);
    const float al = __builtin_amdgcn_exp2f(mi - mn);
    float p[8][4];
    float ls = 0.f;
    #pragma unroll
    for (int t = 0; t < 8; t++)
      #pragma unroll
      for (int rr = 0; rr < 4; rr++) {
        p[t][rr] = __builtin_amdgcn_exp2f(st[t][rr] - mn);
        ls += p[t][rr];
      }
    ls += __shfl_xor(ls, 16);
    ls += __shfl_xor(ls, 32);
    li = al * li + ls;
    mi = mn;

    #pragma unroll
    for (int t = 0; t < 8; t++) {
      const unsigned u0 = fbits(p[t][0]) + 0x8000u;
      const unsigned u1 = fbits(p[t][1]) + 0x8000u;
      const unsigned u2 = fbits(p[t][2]) + 0x8000u;
      const unsigned u3 = fbits(p[t][3]) + 0x8000u;
      uint2 pk;
      pk.x = __builtin_amdgcn_perm(u1, u0, 0x07060302u);
      pk.y = __builtin_amdgcn_perm(u3, u2, 0x07060302u);
      const int cw = t * 2 + (quad >> 1);
      const int sc = (cw & 8) | ((cw & 7) ^ rx);
      *(uint2*)(pw + r * 128 + (sc << 3) + (quad & 1) * 4) = pk;
    }

    float alo[4];
    #pragma unroll
    for (int rr = 0; rr < 4; rr++) alo[rr] = __shfl(al, quad * 4 + rr);
    #pragma unroll
    for (int nt = 0; nt < 4; nt++)
      #pragma unroll
      for (int rr = 0; rr < 4; rr++) o[nt][rr] *= alo[rr];

    asm volatile("s_waitcnt lgkmcnt(0)" ::: "memory");

    #pragma unroll
    for (int kc = 0; kc < 4; kc++) {
      const int c = kc * 4 + quad;
      const int sc = (c & 8) | ((c & 7) ^ rx);
      s8v ap = *(const s8v*)(pw + r * 128 + (sc << 3));
      #pragma unroll
      for (int nt = 0; nt < 4; nt++) {
        s8v bv = *(const s8v*)(Vsh + (nt * 16 + r) * 128 + (sc << 3));
        o[nt] = MFMA16(ap, bv, o[nt]);
      }
    }
  }

  const int h = bh & 15, b = bh >> 4;
  const float linv = 1.f / li;
  #pragma unroll
  for (int rr = 0; rr < 4; rr++) {
    const float inv = __shfl(linv, quad * 4 + rr);
    const size_t orow = ((size_t)(b * 2048 + q0 + quad * 4 + rr)) * 1024 + h * 64;
    #pragma unroll
    for (int nt = 0; nt < 4; nt++)
      attn[orow + nt * 16 + r] = f2bf(o[nt][rr] * inv);
  }
}

// ---------------------------------------------------------------------------
// 8) RMSNorm3 + mlp modulation -> nm bf16
// ---------------------------------------------------------------------------
__launch_bounds__(256)
__global__ void rms3_mod(const float* __restrict__ h, const float* __restrict__ emb,
                         const float* __restrict__ w3, ushort_t* __restrict__ nm)
{
  const int row = blockIdx.x, b = row >> 11, tid = threadIdx.x;
  const float* hr = h + (size_t)row * 1024;
  const int c = tid * 4;
  float4 v = *(const float4*)(hr + c);
  float s2 = v.x*v.x + v.y*v.y + v.z*v.z + v.w*v.w;
  #pragma unroll
  for (int m = 32; m; m >>= 1) s2 += __shfl_down(s2, m);
  __shared__ float red[4];
  const int wave = tid >> 6, lane = tid & 63;
  if (!lane) red[wave] = s2;
  __syncthreads();
  const float rms = rsqrtf((red[0] + red[1] + red[2] + red[3]) * (1.f / 1024.f) + 1e-6f);
  const float* sh = emb + b * 6144 + 3072;
  const float* sc = emb + b * 6144 + 4096;
  float4 shv = *(const float4*)(sh + c);
  float4 scv = *(const float4*)(sc + c);
  float4 wv  = *(const float4*)(w3 + c);
  s4v ov;
  ov[0] = (short)f2bf(v.x * rms * wv.x * (1.f + scv.x) + shv.x);
  ov[1] = (short)f2bf(v.y * rms * wv.y * (1.f + scv.y) + shv.y);
  ov[2] = (short)f2bf(v.z * rms * wv.z * (1.f + scv.z) + shv.z);
  ov[3] = (short)f2bf(v.w * rms * wv.w * (1.f + scv.w) + shv.w);
  *(s4v*)(nm + (size_t)row * 1024 + c) = ov;
}

// ---------------------------------------------------------------------------
// host launcher
// ---------------------------------------------------------------------------
extern "C" void kernel_launch(void* const* d_in, const int* in_sizes, int n_in,
                              void* d_out, int out_size, void* d_ws, size_t ws_size,
                              hipStream_t stream)
{
  const float* x    = (const float*)d_in[0];
  const float* ts   = (const float*)d_in[1];
  const float* rope = (const float*)d_in[2];
  const float* adw  = (const float*)d_in[3];
  const float* adb  = (const float*)d_in[4];
  const float* wq   = (const float*)d_in[5];
  const float* wk   = (const float*)d_in[6];
  const float* wv   = (const float*)d_in[7];
  const float* wo   = (const float*)d_in[8];
  const float* qnw  = (const float*)d_in[9];
  const float* knw  = (const float*)d_in[10];
  const float* n3w  = (const float*)d_in[11];
  const float* f1w  = (const float*)d_in[12];
  const float* f1b  = (const float*)d_in[13];
  const float* f2w  = (const float*)d_in[14];
  const float* f2b  = (const float*)d_in[15];

  char* ws = (char*)d_ws;
  ushort_t* WQKV = (ushort_t*)(ws + 0);          //  6 MB
  ushort_t* WO   = (ushort_t*)(ws + 6291456);    //  2 MB
  ushort_t* F1   = (ushort_t*)(ws + 8388608);    //  8 MB
  ushort_t* F2   = (ushort_t*)(ws + 16777216);   //  8 MB
  float*    EMB  = (float*)   (ws + 25165824);   //  48 KB
  float*    H    = (float*)   (ws + 25214976);   // 16 MB
  ushort_t* XM   = (ushort_t*)(ws + 41992192);   //  8 MB  (later: ATTN)
  ushort_t* QKV  = (ushort_t*)(ws + 50380800);   // 24 MB  (later: NM)
  ushort_t* QR   = (ushort_t*)(ws + 75546624);   //  8 MB  (later: FF1 spans 32MB)
  ushort_t* KR   = (ushort_t*)(ws + 83935232);   //  8 MB
  ushort_t* VR   = (ushort_t*)(ws + 92323840);   //  8 MB
  ushort_t* VT   = (ushort_t*)(ws + 100712448);  //  8 MB
  ushort_t* ATTN = XM;
  ushort_t* NM   = QKV;
  ushort_t* FF1  = QR;

  convert_w<<<12288, 256, 0, stream>>>(wq, wk, wv, wo, f1w, f2w, WQKV, WO, F1, F2);
  adaln<<<1536, 256, 0, stream>>>(ts, adw, adb, EMB);
  ln_mod<<<4096, 256, 0, stream>>>(x, EMB, XM);
  gemm_bt<0, 128><<<dim3(24, 32), 256, 0, stream>>>(XM, WQKV, 1024, 3072,
      QKV, nullptr, nullptr, nullptr, nullptr, 0);
  qkv_post<<<4096, 256, 0, stream>>>(QKV, rope, qnw, knw, QR, KR, VR);
  vtrans<<<1024, 256, 0, stream>>>(VR, VT);
  flash<<<1024, 256, 0, stream>>>(QR, KR, VT, ATTN);
  gemm_bt<1, 64><<<dim3(16, 32), 256, 0, stream>>>(ATTN, WO, 1024, 1024,
      nullptr, H, nullptr, x, EMB, 2048);
  rms3_mod<<<4096, 256, 0, stream>>>(H, EMB, n3w, NM);
  gemm_bt<2, 128><<<dim3(32, 32), 256, 0, stream>>>(NM, F1, 1024, 4096,
      FF1, nullptr, f1b, nullptr, nullptr, 0);
  gemm_bt<3, 64><<<dim3(16, 32), 256, 0, stream>>>(FF1, F2, 4096, 1024,
      nullptr, (float*)d_out, f2b, H, EMB, 5120);
}

// Round 8
// 421.166 us; speedup vs baseline: 1.3406x; 1.0163x over previous
//
#include <hip/hip_runtime.h>
#include <cstdint>
#include <cstddef>

typedef unsigned short ushort_t;
typedef __attribute__((ext_vector_type(8))) short s8v;
typedef __attribute__((ext_vector_type(4))) short s4v;
typedef __attribute__((ext_vector_type(4))) float f4v;

#define MFMA16(a, b, c) __builtin_amdgcn_mfma_f32_16x16x32_bf16(a, b, c, 0, 0, 0)

__device__ __forceinline__ ushort_t f2bf(float f) {
  union { float f; unsigned u; } a; a.f = f;
  return (ushort_t)((a.u + 0x7fffu + ((a.u >> 16) & 1u)) >> 16);
}
__device__ __forceinline__ float bf2f(ushort_t h) {
  union { unsigned u; float f; } a; a.u = ((unsigned)h) << 16; return a.f;
}
__device__ __forceinline__ unsigned fbits(float f) {
  union { float f; unsigned u; } a; a.f = f; return a.u;
}

// async global->LDS, 16B per lane; LDS dest is wave-uniform base + lane*16
__device__ __forceinline__ void gload16(const void* g, void* l) {
  __builtin_amdgcn_global_load_lds(
      (__attribute__((address_space(1))) void*)(uintptr_t)g,
      (__attribute__((address_space(3))) void*)(unsigned)(uintptr_t)l,
      16, 0, 0);
}

// ---------------------------------------------------------------------------
// 1) fp32 -> bf16 weight conversion. grid = 12288 blocks x 256 (1024 elem/blk)
// ---------------------------------------------------------------------------
__launch_bounds__(256)
__global__ void convert_w(const float* __restrict__ wq, const float* __restrict__ wk,
                          const float* __restrict__ wv, const float* __restrict__ wo,
                          const float* __restrict__ f1, const float* __restrict__ f2,
                          ushort_t* __restrict__ dqkv, ushort_t* __restrict__ dwo,
                          ushort_t* __restrict__ df1, ushort_t* __restrict__ df2)
{
  const int blk = blockIdx.x;
  const float* src; ushort_t* dst; int off;
  if      (blk < 1024) { src = wq; dst = dqkv;            off = blk; }
  else if (blk < 2048) { src = wk; dst = dqkv + 1048576;  off = blk - 1024; }
  else if (blk < 3072) { src = wv; dst = dqkv + 2097152;  off = blk - 2048; }
  else if (blk < 4096) { src = wo; dst = dwo;             off = blk - 3072; }
  else if (blk < 8192) { src = f1; dst = df1;             off = blk - 4096; }
  else                 { src = f2; dst = df2;             off = blk - 8192; }
  const int idx = off * 1024 + threadIdx.x * 4;
  float4 v = *(const float4*)(src + idx);
  s4v o;
  o[0] = (short)f2bf(v.x); o[1] = (short)f2bf(v.y);
  o[2] = (short)f2bf(v.z); o[3] = (short)f2bf(v.w);
  *(s4v*)(dst + idx) = o;
}

// ---------------------------------------------------------------------------
// 2) adaln: emb[b][j] = sum_d silu(ts[b][d]) * w[j][d] + bias[j]
// ---------------------------------------------------------------------------
__launch_bounds__(256)
__global__ void adaln(const float* __restrict__ ts, const float* __restrict__ w,
                      const float* __restrict__ bias, float* __restrict__ emb)
{
  const int j = blockIdx.x * 4 + (threadIdx.x >> 6);
  const int lane = threadIdx.x & 63;
  const float* wr = w + (size_t)j * 1024;
  float s0 = 0.f, s1 = 0.f;
  for (int i = lane; i < 1024; i += 64) {
    const float wv = wr[i];
    const float t0 = ts[i], t1 = ts[1024 + i];
    const float e0 = __builtin_amdgcn_exp2f(-1.4426950409f * t0);
    const float e1 = __builtin_amdgcn_exp2f(-1.4426950409f * t1);
    s0 += wv * t0 * __builtin_amdgcn_rcpf(1.f + e0);
    s1 += wv * t1 * __builtin_amdgcn_rcpf(1.f + e1);
  }
  #pragma unroll
  for (int m = 32; m; m >>= 1) { s0 += __shfl_down(s0, m); s1 += __shfl_down(s1, m); }
  if (!lane) { emb[j] = s0 + bias[j]; emb[6144 + j] = s1 + bias[j]; }
}

// ---------------------------------------------------------------------------
// 3) LayerNorm + msa modulation -> xm bf16. one block per row.
// ---------------------------------------------------------------------------
__launch_bounds__(256)
__global__ void ln_mod(const float* __restrict__ x, const float* __restrict__ emb,
                       ushort_t* __restrict__ xm)
{
  const int row = blockIdx.x, b = row >> 11, tid = threadIdx.x;
  const float* xr = x + (size_t)row * 1024;
  const int c = tid * 4;
  float4 v = *(const float4*)(xr + c);
  float s  = v.x + v.y + v.z + v.w;
  float s2 = v.x*v.x + v.y*v.y + v.z*v.z + v.w*v.w;
  #pragma unroll
  for (int m = 32; m; m >>= 1) { s += __shfl_down(s, m); s2 += __shfl_down(s2, m); }
  __shared__ float red[8];
  const int wave = tid >> 6, lane = tid & 63;
  if (!lane) { red[wave] = s; red[4 + wave] = s2; }
  __syncthreads();
  const float mu = (red[0] + red[1] + red[2] + red[3]) * (1.f / 1024.f);
  const float ms = (red[4] + red[5] + red[6] + red[7]) * (1.f / 1024.f);
  const float rstd = rsqrtf(ms - mu * mu + 1e-6f);
  const float* sh = emb + b * 6144;
  const float* sc = emb + b * 6144 + 1024;
  float4 shv = *(const float4*)(sh + c);
  float4 scv = *(const float4*)(sc + c);
  s4v ov;
  ov[0] = (short)f2bf((v.x - mu) * rstd * (1.f + scv.x) + shv.x);
  ov[1] = (short)f2bf((v.y - mu) * rstd * (1.f + scv.y) + shv.y);
  ov[2] = (short)f2bf((v.z - mu) * rstd * (1.f + scv.z) + shv.z);
  ov[3] = (short)f2bf((v.w - mu) * rstd * (1.f + scv.w) + shv.w);
  *(s4v*)(xm + (size_t)row * 1024 + c) = ov;
}

// ---------------------------------------------------------------------------
// 4a) bf16 B^T GEMM, 128 x TN tile, 4 waves, static dbuf.
//     Used for QKV (TN=128), WO/FC2 (TN=64).
// ---------------------------------------------------------------------------
template<int EPI, int TN>
__launch_bounds__(256)
__global__ void gemm_bt(const ushort_t* __restrict__ A, const ushort_t* __restrict__ Bw,
                        int K, int N,
                        ushort_t* __restrict__ outb, float* __restrict__ outf,
                        const float* __restrict__ bias, const float* __restrict__ resid,
                        const float* __restrict__ emb, int gate_off)
{
  constexpr int JN = TN / 32;
  constexpr int BUFB = TN * 32;
  __shared__ ushort_t As0[128 * 32], As1[128 * 32];
  __shared__ ushort_t Bs0[BUFB],    Bs1[BUFB];
  const int tid = threadIdx.x;
  const int wave = tid >> 6, lane = tid & 63;
  const int quad = lane >> 4, r = lane & 15;
  const int m0 = blockIdx.y * 128, n0 = blockIdx.x * TN;
  const int wm = (wave >> 1) * 64, wn = (wave & 1) * (TN / 2);

  const int srow = wave * 16 + (lane >> 2);
  const int scol = (lane & 3) * 8;
  const ushort_t* ag = A  + (size_t)(m0 + srow) * K + scol;
  const ushort_t* bg = Bw + (size_t)(n0 + srow) * K + scol;
  const size_t rowK64 = (size_t)64 * K;

  f4v acc[4][JN] = {};

  auto stage = [&](ushort_t* as, ushort_t* bs) {
    gload16(ag,          as + wave * 512);
    gload16(ag + rowK64, as + wave * 512 + 2048);
    gload16(bg,          bs + wave * 512);
    if (TN == 128) gload16(bg + rowK64, bs + wave * 512 + 2048);
    ag += 32; bg += 32;
  };
  auto compute = [&](const ushort_t* ab, const ushort_t* bb) {
    s8v af[4], bf[JN];
    #pragma unroll
    for (int i = 0; i < 4; i++)
      af[i] = *(const s8v*)(ab + (wm + i * 16 + r) * 32 + quad * 8);
    #pragma unroll
    for (int j = 0; j < JN; j++)
      bf[j] = *(const s8v*)(bb + (wn + j * 16 + r) * 32 + quad * 8);
    #pragma unroll
    for (int i = 0; i < 4; i++)
      #pragma unroll
      for (int j = 0; j < JN; j++)
        acc[i][j] = MFMA16(af[i], bf[j], acc[i][j]);
  };

  stage(As0, Bs0);
  __syncthreads();
  const int R = (K >> 6) - 1;
  for (int it = 0; it < R; it++) {
    stage(As1, Bs1);
    compute(As0, Bs0);
    __syncthreads();
    stage(As0, Bs0);
    compute(As1, Bs1);
    __syncthreads();
  }
  stage(As1, Bs1);
  compute(As0, Bs0);
  __syncthreads();
  compute(As1, Bs1);

  const int bblk = m0 >> 11;
  #pragma unroll
  for (int j = 0; j < JN; j++) {
    const int col = n0 + wn + j * 16 + r;
    float bj = 0.f, gj = 0.f;
    if (EPI == 2 || EPI == 3) bj = bias[col];
    if (EPI == 1 || EPI == 3) gj = emb[bblk * 6144 + gate_off + col];
    #pragma unroll
    for (int i = 0; i < 4; i++) {
      const int row = m0 + wm + i * 16 + quad * 4;
      #pragma unroll
      for (int rr = 0; rr < 4; rr++) {
        float v = acc[i][j][rr];
        const size_t idx = (size_t)(row + rr) * N + col;
        if (EPI == 0) {
          outb[idx] = f2bf(v);
        } else if (EPI == 1) {
          outf[idx] = resid[idx] + gj * v;
        } else if (EPI == 2) {
          v += bj;
          const float t = fmaf(v * v, 0.1029436f, 2.3022083f);
          const float e = __builtin_amdgcn_exp2f(-v * t);
          outb[idx] = f2bf(v * __builtin_amdgcn_rcpf(1.f + e));
        } else {
          outf[idx] = resid[idx] + gj * (v + bj);
        }
      }
    }
  }
}

// ---------------------------------------------------------------------------
// 4b) gemm256: 256x128 tile, 4 waves of 128x64 (acc 8x4), static dbuf.
//     Grid for FC1: 32 x 16 = 512 blocks = 2/CU exact. bias+gelu epilogue.
// ---------------------------------------------------------------------------
__launch_bounds__(256, 2)
__global__ void gemm256(const ushort_t* __restrict__ A, const ushort_t* __restrict__ Bw,
                        int K, int N,
                        ushort_t* __restrict__ outb, const float* __restrict__ bias)
{
  __shared__ ushort_t As0[256 * 32], As1[256 * 32];
  __shared__ ushort_t Bs0[128 * 32], Bs1[128 * 32];
  const int tid = threadIdx.x;
  const int wave = tid >> 6, lane = tid & 63;
  const int quad = lane >> 4, r = lane & 15;
  const int m0 = blockIdx.y * 256, n0 = blockIdx.x * 128;
  const int wm = (wave >> 1) * 128, wn = (wave & 1) * 64;

  const int srow = wave * 16 + (lane >> 2);
  const int scol = (lane & 3) * 8;
  const ushort_t* ag = A  + (size_t)(m0 + srow) * K + scol;
  const ushort_t* bg = Bw + (size_t)(n0 + srow) * K + scol;
  const size_t rowK64 = (size_t)64 * K;

  f4v acc[8][4] = {};

  auto stage = [&](ushort_t* as, ushort_t* bs) {
    #pragma unroll
    for (int sg = 0; sg < 4; sg++)
      gload16(ag + sg * rowK64, as + sg * 2048 + wave * 512);
    #pragma unroll
    for (int sg = 0; sg < 2; sg++)
      gload16(bg + sg * rowK64, bs + sg * 2048 + wave * 512);
    ag += 32; bg += 32;
  };
  auto compute = [&](const ushort_t* ab, const ushort_t* bb) {
    s8v bf[4];
    #pragma unroll
    for (int j = 0; j < 4; j++)
      bf[j] = *(const s8v*)(bb + (wn + j * 16 + r) * 32 + quad * 8);
    #pragma unroll
    for (int i = 0; i < 8; i++) {
      s8v af = *(const s8v*)(ab + (wm + i * 16 + r) * 32 + quad * 8);
      #pragma unroll
      for (int j = 0; j < 4; j++)
        acc[i][j] = MFMA16(af, bf[j], acc[i][j]);
    }
  };

  stage(As0, Bs0);
  __syncthreads();
  const int R = (K >> 6) - 1;
  for (int it = 0; it < R; it++) {
    stage(As1, Bs1);
    compute(As0, Bs0);
    __syncthreads();
    stage(As0, Bs0);
    compute(As1, Bs1);
    __syncthreads();
  }
  stage(As1, Bs1);
  compute(As0, Bs0);
  __syncthreads();
  compute(As1, Bs1);

  #pragma unroll
  for (int j = 0; j < 4; j++) {
    const int col = n0 + wn + j * 16 + r;
    const float bj = bias[col];
    #pragma unroll
    for (int i = 0; i < 8; i++) {
      const int row = m0 + wm + i * 16 + quad * 4;
      #pragma unroll
      for (int rr = 0; rr < 4; rr++) {
        float v = acc[i][j][rr] + bj;
        const float t = fmaf(v * v, 0.1029436f, 2.3022083f);
        const float e = __builtin_amdgcn_exp2f(-v * t);
        outb[(size_t)(row + rr) * N + col] =
            f2bf(v * __builtin_amdgcn_rcpf(1.f + e));
      }
    }
  }
}

// ---------------------------------------------------------------------------
// 5) QKV post: RMSNorm + RoPE + layout.
// ---------------------------------------------------------------------------
__launch_bounds__(256)
__global__ void qkv_post(const ushort_t* __restrict__ qkv, const float* __restrict__ rope,
                         const float* __restrict__ qw, const float* __restrict__ kw,
                         ushort_t* __restrict__ q_r, ushort_t* __restrict__ k_r,
                         ushort_t* __restrict__ v_r)
{
  const int row = blockIdx.x, b = row >> 11, s = row & 2047, tid = threadIdx.x;
  const ushort_t* base = qkv + (size_t)row * 3072;
  const int c = tid * 4;
  s4v qv = *(const s4v*)(base + c);
  s4v kv = *(const s4v*)(base + 1024 + c);
  s4v vv = *(const s4v*)(base + 2048 + c);
  float qf[4], kf[4]; float sq = 0.f, sk = 0.f;
  #pragma unroll
  for (int i = 0; i < 4; i++) {
    qf[i] = bf2f((ushort_t)qv[i]); kf[i] = bf2f((ushort_t)kv[i]);
    sq += qf[i] * qf[i]; sk += kf[i] * kf[i];
  }
  #pragma unroll
  for (int m = 32; m; m >>= 1) { sq += __shfl_down(sq, m); sk += __shfl_down(sk, m); }
  __shared__ float red[8];
  const int wave = tid >> 6, lane = tid & 63;
  if (!lane) { red[wave] = sq; red[4 + wave] = sk; }
  __syncthreads();
  const float rq = rsqrtf((red[0]+red[1]+red[2]+red[3]) * (1.f/1024.f) + 1e-6f)
                   * 0.18033688011112042f;  // fold 0.125*log2(e) into Q
  const float rk = rsqrtf((red[4]+red[5]+red[6]+red[7]) * (1.f/1024.f) + 1e-6f);

  const int h = c >> 6, d = c & 63;
  const float* rp = rope + ((size_t)s * 64 + d) * 2;
  float4 r01 = *(const float4*)(rp);
  float4 r23 = *(const float4*)(rp + 4);
  const float q0 = qf[0]*rq*qw[c], q1 = qf[1]*rq*qw[c+1];
  const float q2 = qf[2]*rq*qw[c+2], q3 = qf[3]*rq*qw[c+3];
  const float k0 = kf[0]*rk*kw[c], k1 = kf[1]*rk*kw[c+1];
  const float k2 = kf[2]*rk*kw[c+2], k3 = kf[3]*rk*kw[c+3];
  s4v qo, ko;
  qo[0] = (short)f2bf(q0 * r01.x - q1 * r01.y);
  qo[1] = (short)f2bf(q1 * r01.z + q0 * r01.w);
  qo[2] = (short)f2bf(q2 * r23.x - q3 * r23.y);
  qo[3] = (short)f2bf(q3 * r23.z + q2 * r23.w);
  ko[0] = (short)f2bf(k0 * r01.x - k1 * r01.y);
  ko[1] = (short)f2bf(k1 * r01.z + k0 * r01.w);
  ko[2] = (short)f2bf(k2 * r23.x - k3 * r23.y);
  ko[3] = (short)f2bf(k3 * r23.z + k2 * r23.w);
  const size_t rowbase = ((size_t)(b * 16 + h) * 2048 + s) * 64;
  const int d_s = (((d >> 3) ^ (s & 7)) << 3) | (d & 7);   // K chunk swizzle
  *(s4v*)(q_r + rowbase + d) = qo;
  *(s4v*)(k_r + rowbase + d_s) = ko;
  *(s4v*)(v_r + rowbase + d) = vv;
}

// ---------------------------------------------------------------------------
// 6) V transpose.
// ---------------------------------------------------------------------------
__launch_bounds__(256)
__global__ void vtrans(const ushort_t* __restrict__ v_r, ushort_t* __restrict__ v_t)
{
  const int bh = blockIdx.x >> 5, st = blockIdx.x & 31;
  const int s0 = st * 64;
  __shared__ ushort_t tile[64 * 72];
  const int tid = threadIdx.x;
  #pragma unroll
  for (int rep = 0; rep < 2; rep++) {
    const int idx = rep * 256 + tid;
    const int sr = idx >> 3, dc = (idx & 7) << 3;
    s8v val = *(const s8v*)(v_r + ((size_t)bh * 2048 + s0 + sr) * 64 + dc);
    *(s8v*)(tile + sr * 72 + dc) = val;
  }
  __syncthreads();
  #pragma unroll
  for (int rep = 0; rep < 2; rep++) {
    const int idx = rep * 256 + tid;
    const int d = idx >> 3;
    const int scs = (((idx & 7) ^ (d & 7)) << 3);
    s8v val;
    const int sc = (idx & 7) << 3;
    #pragma unroll
    for (int j = 0; j < 8; j++) val[j] = (short)tile[(sc + j) * 72 + d];
    *(s8v*)(v_t + ((size_t)bh * 64 + d) * 2048 + s0 + scs) = val;
  }
}

// ---------------------------------------------------------------------------
// 7) Flash attention: R4-proven v3 structure (16KB Psh, single PV phase)
//    + depth-5 tree reductions (registers only). LDS 48KB.
// ---------------------------------------------------------------------------
__launch_bounds__(256)
__global__ void flash(const ushort_t* __restrict__ q_r, const ushort_t* __restrict__ k_r,
                      const ushort_t* __restrict__ v_t, ushort_t* __restrict__ attn)
{
  __shared__ ushort_t Ksh[128 * 64];     // [key][d], 8 chunks ^(key&7)
  __shared__ ushort_t Vsh[64 * 128];     // [d][key], 16 chunks (c&8)|((c&7)^(d&7))
  __shared__ ushort_t Psh[4][16 * 128];  // per-wave [q][key], same 16-chunk swizzle
  const int bh = blockIdx.x >> 5, qb = blockIdx.x & 31;
  const int tid = threadIdx.x, wave = tid >> 6, lane = tid & 63;
  const int quad = lane >> 4, r = lane & 15;
  const int rx = r & 7;
  const int q0 = qb * 64 + wave * 16;
  const size_t bhS = (size_t)bh * 2048;

  s8v aq0 = *(const s8v*)(q_r + (bhS + q0 + r) * 64 + quad * 8);
  s8v aq1 = *(const s8v*)(q_r + (bhS + q0 + r) * 64 + 32 + quad * 8);

  f4v o[4] = {};
  float mi = -1e30f, li = 0.f;

  const ushort_t* kg = k_r + (bhS + wave * 32 + (lane >> 3)) * 64 + (lane & 7) * 8;
  ushort_t* kl = Ksh + wave * 2048 + lane * 8;
  const ushort_t* vg = v_t + ((size_t)bh * 64 + wave * 16 + (lane >> 4)) * 2048
                       + (lane & 15) * 8;
  ushort_t* vl = Vsh + (wave * 16 + (lane >> 4)) * 128 + (lane & 15) * 8;
  ushort_t* pw = &Psh[wave][0];

  for (int kb = 0; kb < 2048; kb += 128) {
    __syncthreads();
    #pragma unroll
    for (int c = 0; c < 4; c++) {
      gload16(kg + (size_t)(kb + c * 8) * 64, kl + c * 512);
      gload16(vg + kb + (size_t)(c * 4) * 2048, vl + c * 512);
    }
    __syncthreads();

    // S^T[key][q]: 8 row-tiles of 16 keys
    f4v st[8];
    #pragma unroll
    for (int t = 0; t < 8; t++) {
      const ushort_t* krow = Ksh + (t * 16 + r) * 64;
      s8v k0 = *(const s8v*)(krow + ((quad ^ rx) << 3));
      s8v k1 = *(const s8v*)(krow + (((4 + quad) ^ rx) << 3));
      f4v z = {};
      z = MFMA16(k0, aq0, z);
      z = MFMA16(k1, aq1, z);
      st[t] = z;
    }

    // max: depth-5 tree + 2 cross-lane hops
    float m4[8];
    #pragma unroll
    for (int t = 0; t < 8; t++)
      m4[t] = fmaxf(fmaxf(st[t][0], st[t][1]), fmaxf(st[t][2], st[t][3]));
    float mloc = fmaxf(fmaxf(fmaxf(m4[0], m4[1]), fmaxf(m4[2], m4[3])),
                       fmaxf(fmaxf(m4[4], m4[5]), fmaxf(m4[6], m4[7])));
    mloc = fmaxf(mloc, __shfl_xor(mloc, 16));
    mloc = fmaxf(mloc, __shfl_xor(mloc, 32));
    const float mn = fmaxf(mi, mloc);
    const float al = __builtin_amdgcn_exp2f(mi - mn);

    float p[8][4];
    uint2 pk[8];
    #pragma unroll
    for (int t = 0; t < 8; t++) {
      #pragma unroll
      for (int rr = 0; rr < 4; rr++)
        p[t][rr] = __builtin_amdgcn_exp2f(st[t][rr] - mn);
      const unsigned u0 = fbits(p[t][0]) + 0x8000u;
      const unsigned u1 = fbits(p[t][1]) + 0x8000u;
      const unsigned u2 = fbits(p[t][2]) + 0x8000u;
      const unsigned u3 = fbits(p[t][3]) + 0x8000u;
      pk[t].x = __builtin_amdgcn_perm(u1, u0, 0x07060302u);
      pk[t].y = __builtin_amdgcn_perm(u3, u2, 0x07060302u);
    }

    // pack P -> Psh (16 chunks, swizzled), b64 writes
    #pragma unroll
    for (int t = 0; t < 8; t++) {
      const int cw = t * 2 + (quad >> 1);
      const int sc = (cw & 8) | ((cw & 7) ^ rx);
      *(uint2*)(pw + r * 128 + (sc << 3) + (quad & 1) * 4) = pk[t];
    }

    // rescale O (independent of P writes)
    float alo[4];
    #pragma unroll
    for (int rr = 0; rr < 4; rr++) alo[rr] = __shfl(al, quad * 4 + rr);
    #pragma unroll
    for (int nt = 0; nt < 4; nt++)
      #pragma unroll
      for (int rr = 0; rr < 4; rr++) o[nt][rr] *= alo[rr];

    // sum: depth-5 tree + 2 hops
    float s4r[8];
    #pragma unroll
    for (int t = 0; t < 8; t++)
      s4r[t] = (p[t][0] + p[t][1]) + (p[t][2] + p[t][3]);
    float ls = ((s4r[0] + s4r[1]) + (s4r[2] + s4r[3])) +
               ((s4r[4] + s4r[5]) + (s4r[6] + s4r[7]));
    ls += __shfl_xor(ls, 16);
    ls += __shfl_xor(ls, 32);
    li = al * li + ls;
    mi = mn;

    asm volatile("s_waitcnt lgkmcnt(0)" ::: "memory");  // P writes -> reads, same wave

    // O += P * V  (K = 32 keys per MFMA, 4 chunks of the 128-key tile)
    #pragma unroll
    for (int kc = 0; kc < 4; kc++) {
      const int c = kc * 4 + quad;
      const int sc = (c & 8) | ((c & 7) ^ rx);
      s8v ap = *(const s8v*)(pw + r * 128 + (sc << 3));
      #pragma unroll
      for (int nt = 0; nt < 4; nt++) {
        s8v bv = *(const s8v*)(Vsh + (nt * 16 + r) * 128 + (sc << 3));
        o[nt] = MFMA16(ap, bv, o[nt]);
      }
    }
  }

  const int h = bh & 15, b = bh >> 4;
  const float linv = 1.f / li;
  #pragma unroll
  for (int rr = 0; rr < 4; rr++) {
    const float inv = __shfl(linv, quad * 4 + rr);
    const size_t orow = ((size_t)(b * 2048 + q0 + quad * 4 + rr)) * 1024 + h * 64;
    #pragma unroll
    for (int nt = 0; nt < 4; nt++)
      attn[orow + nt * 16 + r] = f2bf(o[nt][rr] * inv);
  }
}

// ---------------------------------------------------------------------------
// 8) RMSNorm3 + mlp modulation -> nm bf16
// ---------------------------------------------------------------------------
__launch_bounds__(256)
__global__ void rms3_mod(const float* __restrict__ h, const float* __restrict__ emb,
                         const float* __restrict__ w3, ushort_t* __restrict__ nm)
{
  const int row = blockIdx.x, b = row >> 11, tid = threadIdx.x;
  const float* hr = h + (size_t)row * 1024;
  const int c = tid * 4;
  float4 v = *(const float4*)(hr + c);
  float s2 = v.x*v.x + v.y*v.y + v.z*v.z + v.w*v.w;
  #pragma unroll
  for (int m = 32; m; m >>= 1) s2 += __shfl_down(s2, m);
  __shared__ float red[4];
  const int wave = tid >> 6, lane = tid & 63;
  if (!lane) red[wave] = s2;
  __syncthreads();
  const float rms = rsqrtf((red[0] + red[1] + red[2] + red[3]) * (1.f / 1024.f) + 1e-6f);
  const float* sh = emb + b * 6144 + 3072;
  const float* sc = emb + b * 6144 + 4096;
  float4 shv = *(const float4*)(sh + c);
  float4 scv = *(const float4*)(sc + c);
  float4 wv  = *(const float4*)(w3 + c);
  s4v ov;
  ov[0] = (short)f2bf(v.x * rms * wv.x * (1.f + scv.x) + shv.x);
  ov[1] = (short)f2bf(v.y * rms * wv.y * (1.f + scv.y) + shv.y);
  ov[2] = (short)f2bf(v.z * rms * wv.z * (1.f + scv.z) + shv.z);
  ov[3] = (short)f2bf(v.w * rms * wv.w * (1.f + scv.w) + shv.w);
  *(s4v*)(nm + (size_t)row * 1024 + c) = ov;
}

// ---------------------------------------------------------------------------
// host launcher
// ---------------------------------------------------------------------------
extern "C" void kernel_launch(void* const* d_in, const int* in_sizes, int n_in,
                              void* d_out, int out_size, void* d_ws, size_t ws_size,
                              hipStream_t stream)
{
  const float* x    = (const float*)d_in[0];
  const float* ts   = (const float*)d_in[1];
  const float* rope = (const float*)d_in[2];
  const float* adw  = (const float*)d_in[3];
  const float* adb  = (const float*)d_in[4];
  const float* wq   = (const float*)d_in[5];
  const float* wk   = (const float*)d_in[6];
  const float* wv   = (const float*)d_in[7];
  const float* wo   = (const float*)d_in[8];
  const float* qnw  = (const float*)d_in[9];
  const float* knw  = (const float*)d_in[10];
  const float* n3w  = (const float*)d_in[11];
  const float* f1w  = (const float*)d_in[12];
  const float* f1b  = (const float*)d_in[13];
  const float* f2w  = (const float*)d_in[14];
  const float* f2b  = (const float*)d_in[15];

  char* ws = (char*)d_ws;
  ushort_t* WQKV = (ushort_t*)(ws + 0);          //  6 MB
  ushort_t* WO   = (ushort_t*)(ws + 6291456);    //  2 MB
  ushort_t* F1   = (ushort_t*)(ws + 8388608);    //  8 MB
  ushort_t* F2   = (ushort_t*)(ws + 16777216);   //  8 MB
  float*    EMB  = (float*)   (ws + 25165824);   //  48 KB
  float*    H    = (float*)   (ws + 25214976);   // 16 MB
  ushort_t* XM   = (ushort_t*)(ws + 41992192);   //  8 MB  (later: ATTN)
  ushort_t* QKV  = (ushort_t*)(ws + 50380800);   // 24 MB  (later: NM)
  ushort_t* QR   = (ushort_t*)(ws + 75546624);   //  8 MB  (later: FF1 spans 32MB)
  ushort_t* KR   = (ushort_t*)(ws + 83935232);   //  8 MB
  ushort_t* VR   = (ushort_t*)(ws + 92323840);   //  8 MB
  ushort_t* VT   = (ushort_t*)(ws + 100712448);  //  8 MB
  ushort_t* ATTN = XM;
  ushort_t* NM   = QKV;
  ushort_t* FF1  = QR;

  convert_w<<<12288, 256, 0, stream>>>(wq, wk, wv, wo, f1w, f2w, WQKV, WO, F1, F2);
  adaln<<<1536, 256, 0, stream>>>(ts, adw, adb, EMB);
  ln_mod<<<4096, 256, 0, stream>>>(x, EMB, XM);
  gemm_bt<0, 128><<<dim3(24, 32), 256, 0, stream>>>(XM, WQKV, 1024, 3072,
      QKV, nullptr, nullptr, nullptr, nullptr, 0);
  qkv_post<<<4096, 256, 0, stream>>>(QKV, rope, qnw, knw, QR, KR, VR);
  vtrans<<<1024, 256, 0, stream>>>(VR, VT);
  flash<<<1024, 256, 0, stream>>>(QR, KR, VT, ATTN);
  gemm_bt<1, 64><<<dim3(16, 32), 256, 0, stream>>>(ATTN, WO, 1024, 1024,
      nullptr, H, nullptr, x, EMB, 2048);
  rms3_mod<<<4096, 256, 0, stream>>>(H, EMB, n3w, NM);
  gemm256<<<dim3(32, 16), 256, 0, stream>>>(NM, F1, 1024, 4096, FF1, f1b);
  gemm_bt<3, 64><<<dim3(16, 32), 256, 0, stream>>>(FF1, F2, 4096, 1024,
      nullptr, (float*)d_out, f2b, H, EMB, 5120);
}